// Round 2
// baseline (749.299 us; speedup 1.0000x reference)
//
#include <hip/hip_runtime.h>
#include <hip/hip_bf16.h>

typedef unsigned short u16;
typedef unsigned long long u64;
typedef __attribute__((ext_vector_type(8))) short bf16x8;
typedef __attribute__((ext_vector_type(4))) float f32x4;

constexpr int NN = 50000;   // nodes
constexpr int NE = 800000;  // edges
constexpr int LM = 1024;
constexpr int HC = 128;
constexpr int OC = 64;

// ---- workspace layout (bytes) ----
constexpr size_t OFF_ROWPTR = 0;          // (NN+1) int
constexpr size_t OFF_CURSOR = 200192;     // NN int
constexpr size_t OFF_PK     = 400384;     // NN u64 (count<<48 | fx32 weight sum)
constexpr size_t OFF_INCL   = 800512;     // NN int
constexpr size_t OFF_BSUM   = 1000704;    // 64 int
constexpr size_t OFF_DIS    = 1000960;    // NN float
constexpr size_t OFF_META   = 1201152;    // NE int2 (src, w-bits)
constexpr size_t OFF_WLT    = 7601408;    // LM*LM u16
constexpr size_t OFF_W1T    = 9698560;    // HC*LM u16
constexpr size_t OFF_H      = 9960704;    // NN*LM u16
constexpr size_t OFF_Y1     = 112360704;  // NN*HC u16
constexpr size_t OFF_Y3     = 125160704;  // NN*OC u16
constexpr size_t OFF_ABF    = 131560704;  // NN*LM u16 (fast path only)
constexpr size_t NEED_FAST  = OFF_ABF + (size_t)NN * LM * 2;  // ~234 MB

__device__ __forceinline__ u16 f2bf(float f) {
    union { float f; unsigned int u; } a; a.f = f;
    unsigned int u = a.u + 0x7FFFu + ((a.u >> 16) & 1u);  // RNE
    return (u16)(u >> 16);
}
__device__ __forceinline__ float bf2f(u16 v) {
    union { unsigned int u; float f; } a; a.u = ((unsigned int)v) << 16;
    return a.f;
}
__device__ __forceinline__ ushort2 pkbf(float a, float b) {
    union { __hip_bfloat162 h; ushort2 u; } cv;
    cv.h = __float22bfloat162_rn(make_float2(a, b));
    return cv.u;
}
__device__ __forceinline__ void async_copy16(u16* lds, const u16* g) {
    __builtin_amdgcn_global_load_lds(
        (const __attribute__((address_space(1))) void*)g,
        (__attribute__((address_space(3))) void*)lds, 16, 0, 0);
}

// ================= fused setup: zero pk + cvt Wl + cvt W1 =========
__global__ void k_setup(u64* __restrict__ pk,
                        const float* __restrict__ Wl, u16* __restrict__ WlT,
                        const float* __restrict__ W1, u16* __restrict__ W1T) {
    int b = blockIdx.x, t = threadIdx.x;
    if (b < 196) {
        int i = b * 256 + t;
        if (i < NN) pk[i] = 0ULL;
    } else if (b < 196 + 1024) {
        __shared__ float sm[32][33];
        int bb = b - 196;
        int n0 = (bb & 31) * 32, k0 = (bb >> 5) * 32;
        int ty = t >> 5, tx = t & 31;
        #pragma unroll
        for (int i = 0; i < 4; i++)
            sm[ty + i * 8][tx] = Wl[(size_t)(k0 + ty + i * 8) * LM + n0 + tx];
        __syncthreads();
        #pragma unroll
        for (int i = 0; i < 4; i++)
            WlT[(size_t)(n0 + ty + i * 8) * LM + k0 + tx] = f2bf(sm[tx][ty + i * 8]);
    } else {
        int idx = (b - 1220) * 256 + t;  // HC*LM, output-major
        if (idx < HC * LM) {
            int o = idx >> 10, k = idx & 1023;
            W1T[idx] = f2bf(W1[(size_t)k * HC + o]);
        }
    }
}

// ================= CSR build =================
__global__ void k_count(const int* __restrict__ ei, const float* __restrict__ ew,
                        u64* __restrict__ pk) {
    int e = blockIdx.x * 256 + threadIdx.x;
    if (e < NE) {
        int d = ei[NE + e];
        u64 add = (1ULL << 48) | (u64)(ew[e] * 4294967296.0);
        atomicAdd(&pk[d], add);
    }
}
__global__ void k_scan1(const u64* __restrict__ pk, int* __restrict__ incl,
                        int* __restrict__ bsum) {
    __shared__ int sm[1024];
    int t = threadIdx.x, idx = blockIdx.x * 1024 + t;
    int v = (idx < NN) ? (int)(pk[idx] >> 48) : 0;
    sm[t] = v; __syncthreads();
    for (int off = 1; off < 1024; off <<= 1) {
        int add = (t >= off) ? sm[t - off] : 0;
        __syncthreads();
        sm[t] += add;
        __syncthreads();
    }
    if (idx < NN) incl[idx] = sm[t];
    if (t == 1023) bsum[blockIdx.x] = sm[t];
}
__global__ void k_scan3(const int* __restrict__ incl, const u64* __restrict__ pk,
                        const int* __restrict__ bsum,
                        int* __restrict__ rowptr, int* __restrict__ cursor,
                        float* __restrict__ dis) {
    int seg = blockIdx.x >> 2;
    int lane = threadIdx.x & 63;
    int v = (lane < seg) ? bsum[lane] : 0;  // seg <= 48 < 64
    #pragma unroll
    for (int off = 32; off > 0; off >>= 1) v += __shfl_down(v, off, 64);
    int boffv = __shfl(v, 0, 64);
    int idx = blockIdx.x * 256 + threadIdx.x;
    if (idx < NN) {
        u64 p = pk[idx];
        int cnt = (int)(p >> 48);
        float deg = (float)((double)(p & 0xFFFFFFFFFFFFULL) * 2.3283064365386963e-10);
        int rp = incl[idx] - cnt + boffv;
        rowptr[idx] = rp;
        cursor[idx] = rp;
        dis[idx] = rsqrtf(1.0f + deg);
    } else if (idx == NN) {
        rowptr[NN] = NE;
    }
}
__global__ void k_fill(const int* __restrict__ ei, const float* __restrict__ ew,
                       const float* __restrict__ dis,
                       int* __restrict__ cursor, int2* __restrict__ meta) {
    int e = blockIdx.x * 256 + threadIdx.x;
    if (e < NE) {
        int s = ei[e];
        int d = ei[NE + e];
        int slot = atomicAdd(&cursor[d], 1);
        meta[slot] = make_int2(s, __float_as_int(ew[e] * dis[s]));
    }
}

// ================= x_out fp32 -> bf16 streaming convert (fast path) ==========
__global__ __launch_bounds__(256) void k_cvtA(const float* __restrict__ A32,
                                              u16* __restrict__ Abf) {
    size_t idx = (size_t)blockIdx.x * 256 + threadIdx.x;  // chunk of 8 elems
    const float* src = A32 + idx * 8;
    float4 v0 = *(const float4*)(src);
    float4 v1 = *(const float4*)(src + 4);
    union { ushort2 u2[4]; bf16x8 v; } pk;
    pk.u2[0] = pkbf(v0.x, v0.y);
    pk.u2[1] = pkbf(v0.z, v0.w);
    pk.u2[2] = pkbf(v1.x, v1.y);
    pk.u2[3] = pkbf(v1.z, v1.w);
    *(bf16x8*)(Abf + idx * 8) = pk.v;
}

// ======== GEMM1c (fast path): 256x256, BK=64, 8-phase counted-vmcnt =========
// m201-style schedule in plain HIP. 512 threads = 8 waves (2M x 4N),
// fragment-interleaved: wave (wr,wc) owns m-frags at f*32+wr*16 (f=0..7) and
// n-frags at n*64+wc*16 (n=0..3). C-quadrant (mh,nh) therefore reads only
// A-half(mh) (rows mh*128..+127) and B-half(nh) -> half-tiles rotate
// independently. Per phase: 12 ds_read_b128 + 1 half staged (2 gload_lds)
// + barrier + lgkmcnt(0) + setprio(1) + 16 MFMA + setprio(0) + barrier.
// vmcnt(4) (= 2 halves in flight) only at phases 4 and 8 -- never 0 in loop.
// LDS: 2 bufs x (A 256x64 + B 256x64) bf16 = 128 KB -> 1 block/CU.
// Swizzle: global-source pre-swizzled (slot^(row&7)), LDS linear, reads
// undo it -> 0 bank conflicts (same scheme as previous gemm1a, measured 0).
__global__ __launch_bounds__(512, 2) void k_gemm1c(
    const u16* __restrict__ Abf, const u16* __restrict__ Bt, u16* __restrict__ Cout,
    const float* __restrict__ xv, const float* __restrict__ cv,
    const float* __restrict__ Wa, const float* __restrict__ Wc,
    const float* __restrict__ bl) {
    __shared__ u16 lsA[2][256 * 64];
    __shared__ u16 lsB[2][256 * 64];
    const int tid = threadIdx.x;
    const int lane = tid & 63, wv = tid >> 6;
    const int fr = lane & 15, qd = lane >> 4;
    const int fx = fr & 7;
    const int wr16 = (wv >> 2) * 16, wc16 = (wv & 3) * 16;
    // XCD swizzle: 784 = 8 * 98, bijective; 4 n-siblings of an m-band adjacent
    int wgid = (blockIdx.x & 7) * 98 + (blockIdx.x >> 3);
    const int bx = wgid >> 2, by = wgid & 3;
    const int m0 = bx * 256, n0 = by * 256;

    // staging geometry: 512 threads, half-tile = 128 rows x 64 k (2 loads/thread)
    const int rl0 = tid >> 3;               // 0..63
    const int k8 = (tid & 7) ^ (rl0 & 7);   // pre-swizzled k-group
    const u16* pA[2][2];
    #pragma unroll
    for (int half = 0; half < 2; half++)
        #pragma unroll
        for (int j = 0; j < 2; j++) {
            int row = m0 + half * 128 + j * 64 + rl0;
            if (row >= NN) row = NN - 1;
            pA[half][j] = Abf + (size_t)row * LM + k8 * 8;
        }
    const u16* pB0 = Bt + (size_t)(n0 + rl0) * LM + k8 * 8;

    f32x4 acc[8][4] = {};

    auto stA = [&](int kt, int half, int b) {
        #pragma unroll
        for (int j = 0; j < 2; j++)
            async_copy16(&lsA[b][(half * 128 + j * 64 + wv * 8) * 64],
                         pA[half][j] + kt * 64);
    };
    auto stB = [&](int kt, int half, int b) {
        #pragma unroll
        for (int j = 0; j < 2; j++)
            async_copy16(&lsB[b][(half * 128 + j * 64 + wv * 8) * 64],
                         pB0 + (size_t)(half * 128 + j * 64) * LM + kt * 64);
    };

    // one phase: ds_reads(quadrant) || stage one half -> barrier -> MFMA -> barrier
    auto gphase = [&](auto BUF, auto MH, auto NH, auto VM, auto&& stage) {
        constexpr int b = decltype(BUF)::value;
        constexpr int mh = decltype(MH)::value;
        constexpr int nh = decltype(NH)::value;
        bf16x8 af[4][2], bq[2][2];
        #pragma unroll
        for (int f4 = 0; f4 < 4; f4++) {
            int rowA = (mh * 4 + f4) * 32 + wr16 + fr;
            #pragma unroll
            for (int kk = 0; kk < 2; kk++)
                af[f4][kk] = *(const bf16x8*)&lsA[b][rowA * 64 + ((kk * 4 + qd) ^ fx) * 8];
        }
        #pragma unroll
        for (int n2 = 0; n2 < 2; n2++) {
            int rowB = (nh * 2 + n2) * 64 + wc16 + fr;
            #pragma unroll
            for (int kk = 0; kk < 2; kk++)
                bq[n2][kk] = *(const bf16x8*)&lsB[b][rowB * 64 + ((kk * 4 + qd) ^ fx) * 8];
        }
        stage();
        asm volatile("" ::: "memory");
        __builtin_amdgcn_s_barrier();
        asm volatile("s_waitcnt lgkmcnt(0)" ::: "memory");
        __builtin_amdgcn_sched_barrier(0);
        __builtin_amdgcn_s_setprio(1);
        #pragma unroll
        for (int kk = 0; kk < 2; kk++)
            #pragma unroll
            for (int f4 = 0; f4 < 4; f4++)
                #pragma unroll
                for (int n2 = 0; n2 < 2; n2++)
                    acc[mh * 4 + f4][nh * 2 + n2] = __builtin_amdgcn_mfma_f32_16x16x32_bf16(
                        af[f4][kk], bq[n2][kk], acc[mh * 4 + f4][nh * 2 + n2], 0, 0, 0);
        __builtin_amdgcn_s_setprio(0);
        asm volatile("" ::: "memory");
        if constexpr (decltype(VM)::value) {
            asm volatile("s_waitcnt vmcnt(4)" ::: "memory");
        }
        __builtin_amdgcn_s_barrier();
        asm volatile("" ::: "memory");
    };
    using c0 = std::integral_constant<int, 0>;
    using c1 = std::integral_constant<int, 1>;
    using bf_ = std::integral_constant<bool, false>;
    using bt_ = std::integral_constant<bool, true>;

    // prologue: A0(0) B0(0) A1(0) B1(0) A0(1) B0(1); wait tile0 complete
    stA(0, 0, 0); stB(0, 0, 0); stA(0, 1, 0); stB(0, 1, 0);
    stA(1, 0, 1); stB(1, 0, 1);
    asm volatile("s_waitcnt vmcnt(4)" ::: "memory");
    __builtin_amdgcn_s_barrier();
    asm volatile("" ::: "memory");

    for (int i = 0; i < 8; ++i) {
        const int E = 2 * i;
        const bool g = (i < 7);
        gphase(c0{}, c0{}, c0{}, bf_{}, [&] { stA(E + 1, 1, 1); });          // P1
        gphase(c0{}, c0{}, c1{}, bf_{}, [&] { stB(E + 1, 1, 1); });          // P2
        gphase(c0{}, c1{}, c0{}, bf_{}, [&] { if (g) stA(E + 2, 0, 0); });   // P3
        gphase(c0{}, c1{}, c1{}, bt_{}, [&] { if (g) stB(E + 2, 0, 0); });   // P4
        gphase(c1{}, c0{}, c0{}, bf_{}, [&] { if (g) stA(E + 2, 1, 0); });   // P5
        gphase(c1{}, c0{}, c1{}, bf_{}, [&] { if (g) stB(E + 2, 1, 0); });   // P6
        gphase(c1{}, c1{}, c0{}, bf_{}, [&] { if (g) stA(E + 3, 0, 1); });   // P7
        gphase(c1{}, c1{}, c1{}, bt_{}, [&] { if (g) stB(E + 3, 0, 1); });   // P8
    }
    asm volatile("s_waitcnt vmcnt(0)" ::: "memory");  // drain before endpgm

    int jj[4]; float waj[4], wcj[4], blj[4];
    #pragma unroll
    for (int n = 0; n < 4; n++) {
        jj[n] = n0 + n * 64 + wc16 + fr;
        waj[n] = Wa[jj[n]]; wcj[n] = Wc[jj[n]]; blj[n] = bl[jj[n]];
    }
    #pragma unroll
    for (int f = 0; f < 8; f++)
        #pragma unroll
        for (int r = 0; r < 4; r++) {
            int row = m0 + f * 32 + wr16 + qd * 4 + r;
            if (row < NN) {
                float xb = xv[row], cb = cv[row];
                #pragma unroll
                for (int n = 0; n < 4; n++) {
                    float v = acc[f][n][r] + xb * waj[n] + cb * wcj[n] + blj[n];
                    Cout[(size_t)row * LM + jj[n]] = f2bf(fmaxf(v, 0.f));
                }
            }
        }
}

// ======== GEMM1f (fallback): 128x256 tile, fp32 A reg-prefetch staging ========
__global__ __launch_bounds__(256, 2) void k_gemm1f(
    const float* __restrict__ A32, const u16* __restrict__ Bt, u16* __restrict__ Cout,
    const float* __restrict__ xv, const float* __restrict__ cv,
    const float* __restrict__ Wa, const float* __restrict__ Wc,
    const float* __restrict__ bl) {
    __shared__ u16 lA[128 * 64];
    __shared__ u16 lB[2][128 * 64];
    const int tid = threadIdx.x;
    const int lane = tid & 63, wv = tid >> 6;
    const int bx = ((blockIdx.x >> 5) << 3) | (blockIdx.x & 7);
    const int by = (blockIdx.x >> 3) & 3;
    if (bx >= 391) return;
    const int m0 = bx * 128, n0 = by * 256;
    const int wm = (wv >> 1) * 64, wn = (wv & 1) * 64;
    const int fr = lane & 15, qd = lane >> 4;

    f32x4 acc[2][4][4] = {};

    int srl[4], sslot[4]; const float* sbase[4];
    float4 pf[8];
    #pragma unroll
    for (int i = 0; i < 4; i++) {
        int cidx = i * 256 + tid;
        srl[i] = cidx >> 3; sslot[i] = cidx & 7;
        int k8 = sslot[i] ^ (srl[i] & 7);
        int row = m0 + srl[i]; if (row >= NN) row = NN - 1;
        sbase[i] = A32 + (size_t)row * LM + k8 * 8;
    }
    #pragma unroll
    for (int i = 0; i < 4; i++) {
        pf[2 * i]     = *(const float4*)(sbase[i]);
        pf[2 * i + 1] = *(const float4*)(sbase[i] + 4);
    }

    for (int kt = 0; kt < 16; kt++) {
        const int k0 = kt << 6;
        __syncthreads();
        #pragma unroll
        for (int h = 0; h < 2; h++)
            #pragma unroll
            for (int i = 0; i < 4; i++) {
                int r0 = i * 32 + wv * 8;
                int rl = r0 + (lane >> 3);
                int slot = lane & 7;
                int k8 = slot ^ (rl & 7);
                const u16* g = Bt + (size_t)(n0 + h * 128 + rl) * LM + k0 + k8 * 8;
                async_copy16(&lB[h][r0 * 64], g);
            }
        #pragma unroll
        for (int i = 0; i < 4; i++) {
            union { ushort2 u2[4]; bf16x8 v; } pk;
            pk.u2[0] = pkbf(pf[2 * i].x, pf[2 * i].y);
            pk.u2[1] = pkbf(pf[2 * i].z, pf[2 * i].w);
            pk.u2[2] = pkbf(pf[2 * i + 1].x, pf[2 * i + 1].y);
            pk.u2[3] = pkbf(pf[2 * i + 1].z, pf[2 * i + 1].w);
            *(bf16x8*)&lA[srl[i] * 64 + sslot[i] * 8] = pk.v;
        }
        __syncthreads();
        if (kt < 15) {
            #pragma unroll
            for (int i = 0; i < 4; i++) {
                pf[2 * i]     = *(const float4*)(sbase[i] + k0 + 64);
                pf[2 * i + 1] = *(const float4*)(sbase[i] + k0 + 68);
            }
        }
        #pragma unroll
        for (int s = 0; s < 2; s++) {
            const int slot = (s * 4 + qd) ^ (fr & 7);
            bf16x8 af[4];
            #pragma unroll
            for (int mi = 0; mi < 4; mi++)
                af[mi] = *(const bf16x8*)&lA[(wm + mi * 16 + fr) * 64 + slot * 8];
            #pragma unroll
            for (int h = 0; h < 2; h++) {
                bf16x8 bfm[4];
                #pragma unroll
                for (int ni = 0; ni < 4; ni++)
                    bfm[ni] = *(const bf16x8*)&lB[h][(wn + ni * 16 + fr) * 64 + slot * 8];
                #pragma unroll
                for (int mi = 0; mi < 4; mi++)
                    #pragma unroll
                    for (int ni = 0; ni < 4; ni++)
                        acc[h][mi][ni] = __builtin_amdgcn_mfma_f32_16x16x32_bf16(
                            af[mi], bfm[ni], acc[h][mi][ni], 0, 0, 0);
            }
        }
    }

    #pragma unroll
    for (int h = 0; h < 2; h++) {
        int jj[4]; float waj[4], wcj[4], blj[4];
        #pragma unroll
        for (int ni = 0; ni < 4; ni++) {
            jj[ni] = n0 + h * 128 + wn + ni * 16 + fr;
            waj[ni] = Wa[jj[ni]]; wcj[ni] = Wc[jj[ni]]; blj[ni] = bl[jj[ni]];
        }
        #pragma unroll
        for (int mi = 0; mi < 4; mi++)
            #pragma unroll
            for (int r = 0; r < 4; r++) {
                int row = m0 + wm + mi * 16 + qd * 4 + r;
                if (row < NN) {
                    float xb = xv[row], cb = cv[row];
                    #pragma unroll
                    for (int ni = 0; ni < 4; ni++) {
                        float v = acc[h][mi][ni][r] + xb * waj[ni] + cb * wcj[ni] + blj[ni];
                        Cout[(size_t)row * LM + jj[ni]] = f2bf(fmaxf(v, 0.f));
                    }
                }
            }
    }
}

// ======== GEMM2: y1 = h @ W1, 64x128 tile ========
__global__ __launch_bounds__(256) void k_gemm2(
    const u16* __restrict__ Abf, const u16* __restrict__ Bt, u16* __restrict__ Cout) {
    __shared__ u16 lA[64 * 64];
    __shared__ u16 lB[128 * 64];
    const int tid = threadIdx.x;
    const int lane = tid & 63, wv = tid >> 6;
    const int m0 = blockIdx.x * 64;
    const int wm = (wv >> 1) * 32, wn = (wv & 1) * 64;
    const int fr = lane & 15, qd = lane >> 4;
    f32x4 acc[2][4] = {};

    for (int kt = 0; kt < 16; kt++) {
        const int k0 = kt << 6;
        __syncthreads();
        #pragma unroll
        for (int i = 0; i < 4; i++) {
            int r0 = i * 32 + wv * 8;
            int rl = r0 + (lane >> 3);
            int slot = lane & 7;
            int k8 = slot ^ (rl & 7);
            const u16* g = Bt + (size_t)rl * LM + k0 + k8 * 8;
            async_copy16(&lB[r0 * 64], g);
        }
        #pragma unroll
        for (int i = 0; i < 2; i++) {
            int r0 = i * 32 + wv * 8;
            int rl = r0 + (lane >> 3);
            int slot = lane & 7;
            int k8 = slot ^ (rl & 7);
            int row = m0 + rl; if (row >= NN) row = NN - 1;
            const u16* g = Abf + (size_t)row * LM + k0 + k8 * 8;
            async_copy16(&lA[r0 * 64], g);
        }
        __syncthreads();
        #pragma unroll
        for (int s = 0; s < 2; s++) {
            const int slot = (s * 4 + qd) ^ (fr & 7);
            bf16x8 af[2], bfm[4];
            #pragma unroll
            for (int mi = 0; mi < 2; mi++)
                af[mi] = *(const bf16x8*)&lA[(wm + mi * 16 + fr) * 64 + slot * 8];
            #pragma unroll
            for (int ni = 0; ni < 4; ni++)
                bfm[ni] = *(const bf16x8*)&lB[(wn + ni * 16 + fr) * 64 + slot * 8];
            #pragma unroll
            for (int mi = 0; mi < 2; mi++)
                #pragma unroll
                for (int ni = 0; ni < 4; ni++)
                    acc[mi][ni] = __builtin_amdgcn_mfma_f32_16x16x32_bf16(
                        af[mi], bfm[ni], acc[mi][ni], 0, 0, 0);
        }
    }
    #pragma unroll
    for (int mi = 0; mi < 2; mi++)
        #pragma unroll
        for (int r = 0; r < 4; r++) {
            int row = m0 + wm + mi * 16 + qd * 4 + r;
            if (row < NN) {
                #pragma unroll
                for (int ni = 0; ni < 4; ni++)
                    Cout[(size_t)row * HC + wn + ni * 16 + fr] = f2bf(acc[mi][ni][r]);
            }
        }
}

// ====== fused agg1 + gemm3 ======
__global__ __launch_bounds__(512) void k_agg1g3(
    const u16* __restrict__ y1, const int* __restrict__ rowptr,
    const int2* __restrict__ meta, const float* __restrict__ dis,
    const float* __restrict__ b1, const float* __restrict__ W3,
    u16* __restrict__ y3) {
    __shared__ float hrow[8][HC];
    int wv = threadIdx.x >> 6, lane = threadIdx.x & 63;
    int node = blockIdx.x * 8 + wv;
    if (node >= NN) return;
    float di = dis[node];
    int p0 = rowptr[node], p1 = rowptr[node + 1];
    ushort2 sv = *(const ushort2*)(y1 + (size_t)node * HC + lane * 2);
    float a0 = di * bf2f(sv.x), a1 = di * bf2f(sv.y);
    #pragma unroll 8
    for (int p = p0; p < p1; ++p) {
        int2 m = meta[p];
        float nm = __int_as_float(m.y);
        ushort2 v = *(const ushort2*)(y1 + (size_t)m.x * HC + lane * 2);
        a0 += nm * bf2f(v.x);
        a1 += nm * bf2f(v.y);
    }
    a0 = fmaxf(di * a0 + b1[lane * 2], 0.f);
    a1 = fmaxf(di * a1 + b1[lane * 2 + 1], 0.f);
    hrow[wv][lane * 2] = a0;
    hrow[wv][lane * 2 + 1] = a1;
    float acc = 0.f;
    #pragma unroll 8
    for (int k = 0; k < HC; ++k)
        acc += hrow[wv][k] * W3[(size_t)k * OC + lane];
    y3[(size_t)node * OC + lane] = f2bf(acc);
}

// ================= aggregation 3 =================
__global__ __launch_bounds__(256) void k_agg3(
    const u16* __restrict__ y3, const int* __restrict__ rowptr,
    const int2* __restrict__ meta, const float* __restrict__ dis,
    const float* __restrict__ b3, float* __restrict__ outp) {
    int node = blockIdx.x * 4 + (threadIdx.x >> 6);
    int lane = threadIdx.x & 63;
    if (node >= NN) return;
    float di = dis[node];
    int p0 = rowptr[node], p1 = rowptr[node + 1];
    float a = di * bf2f(y3[(size_t)node * OC + lane]);
    #pragma unroll 8
    for (int p = p0; p < p1; ++p) {
        int2 m = meta[p];
        a += __int_as_float(m.y) * bf2f(y3[(size_t)m.x * OC + lane]);
    }
    outp[(size_t)node * OC + lane] = di * a + b3[lane];
}

extern "C" void kernel_launch(void* const* d_in, const int* in_sizes, int n_in,
                              void* d_out, int out_size, void* d_ws, size_t ws_size,
                              hipStream_t stream) {
    const float* x    = (const float*)d_in[0];
    const float* xout = (const float*)d_in[1];
    const float* c    = (const float*)d_in[2];
    const int*   ei   = (const int*)d_in[3];
    const float* ew   = (const float*)d_in[4];
    const float* Wa   = (const float*)d_in[5];
    const float* Wc   = (const float*)d_in[6];
    const float* Wl   = (const float*)d_in[7];
    const float* bl   = (const float*)d_in[8];
    const float* W1   = (const float*)d_in[9];
    const float* b1   = (const float*)d_in[10];
    const float* W3   = (const float*)d_in[11];
    const float* b3   = (const float*)d_in[12];
    float* outp = (float*)d_out;

    char* ws = (char*)d_ws;
    int*   rowptr = (int*)(ws + OFF_ROWPTR);
    int*   cursor = (int*)(ws + OFF_CURSOR);
    u64*   pk     = (u64*)(ws + OFF_PK);
    int*   incl   = (int*)(ws + OFF_INCL);
    int*   bsum   = (int*)(ws + OFF_BSUM);
    float* dis    = (float*)(ws + OFF_DIS);
    int2*  meta   = (int2*)(ws + OFF_META);
    u16*   WlT    = (u16*)(ws + OFF_WLT);
    u16*   W1T    = (u16*)(ws + OFF_W1T);
    u16*   hbuf   = (u16*)(ws + OFF_H);
    u16*   y1     = (u16*)(ws + OFF_Y1);
    u16*   y3     = (u16*)(ws + OFF_Y3);
    u16*   Abf    = (u16*)(ws + OFF_ABF);

    k_setup<<<1732, 256, 0, stream>>>(pk, Wl, WlT, W1, W1T);
    k_count<<<3125, 256, 0, stream>>>(ei, ew, pk);
    k_scan1<<<49, 1024, 0, stream>>>(pk, incl, bsum);
    k_scan3<<<196, 256, 0, stream>>>(incl, pk, bsum, rowptr, cursor, dis);
    k_fill <<<3125, 256, 0, stream>>>(ei, ew, dis, cursor, meta);

    if (ws_size >= NEED_FAST) {
        // fast path: pre-convert A to bf16, then 8-phase 256^2 pipelined GEMM1
        k_cvtA  <<<25000, 256, 0, stream>>>(xout, Abf);
        k_gemm1c<<<784, 512, 0, stream>>>(Abf, WlT, hbuf, x, c, Wa, Wc, bl);
    } else {
        k_gemm1f<<<49 * 32, 256, 0, stream>>>(xout, WlT, hbuf, x, c, Wa, Wc, bl);
    }
    // GEMM2: y1 = h @ W1
    k_gemm2<<<782, 256, 0, stream>>>(hbuf, W1T, y1);
    // conv1 aggregation + bias + relu + conv3 linear (fused)
    k_agg1g3<<<6250, 512, 0, stream>>>(y1, rowptr, meta, dis, b1, W3, y3);
    // conv3 aggregation + bias -> out
    k_agg3<<<12500, 256, 0, stream>>>(y3, rowptr, meta, dis, b3, outp);
}

// Round 3
// 663.704 us; speedup vs baseline: 1.1290x; 1.1290x over previous
//
#include <hip/hip_runtime.h>
#include <hip/hip_bf16.h>

typedef unsigned short u16;
typedef unsigned long long u64;
typedef __attribute__((ext_vector_type(8))) short bf16x8;
typedef __attribute__((ext_vector_type(4))) float f32x4;

constexpr int NN = 50000;   // nodes
constexpr int NE = 800000;  // edges
constexpr int LM = 1024;
constexpr int HC = 128;
constexpr int OC = 64;

// ---- workspace layout (bytes) ----
constexpr size_t OFF_ROWPTR = 0;          // (NN+1) int
constexpr size_t OFF_CURSOR = 200192;     // NN int
constexpr size_t OFF_PK     = 400384;     // NN u64 (count<<48 | fx32 weight sum)
constexpr size_t OFF_INCL   = 800512;     // NN int
constexpr size_t OFF_BSUM   = 1000704;    // 64 int
constexpr size_t OFF_DIS    = 1000960;    // NN float
constexpr size_t OFF_META   = 1201152;    // NE int2 (src, w-bits)
constexpr size_t OFF_WLT    = 7601408;    // LM*LM u16
constexpr size_t OFF_W1T    = 9698560;    // HC*LM u16
constexpr size_t OFF_H      = 9960704;    // NN*LM u16
constexpr size_t OFF_Y1     = 112360704;  // NN*HC u16
constexpr size_t OFF_Y3     = 125160704;  // NN*OC u16
constexpr size_t OFF_ABF    = 131560704;  // NN*LM u16 (fast path only)
constexpr size_t NEED_FAST  = OFF_ABF + (size_t)NN * LM * 2;  // ~234 MB

__device__ __forceinline__ u16 f2bf(float f) {
    union { float f; unsigned int u; } a; a.f = f;
    unsigned int u = a.u + 0x7FFFu + ((a.u >> 16) & 1u);  // RNE
    return (u16)(u >> 16);
}
__device__ __forceinline__ float bf2f(u16 v) {
    union { unsigned int u; float f; } a; a.u = ((unsigned int)v) << 16;
    return a.f;
}
__device__ __forceinline__ ushort2 pkbf(float a, float b) {
    union { __hip_bfloat162 h; ushort2 u; } cv;
    cv.h = __float22bfloat162_rn(make_float2(a, b));
    return cv.u;
}
__device__ __forceinline__ void async_copy16(u16* lds, const u16* g) {
    __builtin_amdgcn_global_load_lds(
        (const __attribute__((address_space(1))) void*)g,
        (__attribute__((address_space(3))) void*)lds, 16, 0, 0);
}

// ====== fused setup: zero pk + cvt Wl + cvt W1 + (fast path) cvt x_out ======
// blocks [0,196): zero pk; [196,1220): WlT transpose; [1220,1732): W1T;
// [1732, 26732) (fast path only): x_out fp32 -> bf16 streaming convert.
__global__ void k_setup(u64* __restrict__ pk,
                        const float* __restrict__ Wl, u16* __restrict__ WlT,
                        const float* __restrict__ W1, u16* __restrict__ W1T,
                        const float* __restrict__ A32, u16* __restrict__ Abf) {
    int b = blockIdx.x, t = threadIdx.x;
    if (b >= 1732) {
        size_t idx = (size_t)(b - 1732) * 256 + t;  // chunk of 8 elems, 6.4M total
        const float* src = A32 + idx * 8;
        float4 v0 = *(const float4*)(src);
        float4 v1 = *(const float4*)(src + 4);
        union { ushort2 u2[4]; bf16x8 v; } pk2;
        pk2.u2[0] = pkbf(v0.x, v0.y);
        pk2.u2[1] = pkbf(v0.z, v0.w);
        pk2.u2[2] = pkbf(v1.x, v1.y);
        pk2.u2[3] = pkbf(v1.z, v1.w);
        *(bf16x8*)(Abf + idx * 8) = pk2.v;
    } else if (b < 196) {
        int i = b * 256 + t;
        if (i < NN) pk[i] = 0ULL;
    } else if (b < 196 + 1024) {
        __shared__ float sm[32][33];
        int bb = b - 196;
        int n0 = (bb & 31) * 32, k0 = (bb >> 5) * 32;
        int ty = t >> 5, tx = t & 31;
        #pragma unroll
        for (int i = 0; i < 4; i++)
            sm[ty + i * 8][tx] = Wl[(size_t)(k0 + ty + i * 8) * LM + n0 + tx];
        __syncthreads();
        #pragma unroll
        for (int i = 0; i < 4; i++)
            WlT[(size_t)(n0 + ty + i * 8) * LM + k0 + tx] = f2bf(sm[tx][ty + i * 8]);
    } else {
        int idx = (b - 1220) * 256 + t;  // HC*LM, output-major
        if (idx < HC * LM) {
            int o = idx >> 10, k = idx & 1023;
            W1T[idx] = f2bf(W1[(size_t)k * HC + o]);
        }
    }
}

// ================= CSR build =================
// one u64 atomic per edge: count in [48,64), weight sum fixed-point 2^-32 in [0,48)
__global__ void k_count(const int* __restrict__ ei, const float* __restrict__ ew,
                        u64* __restrict__ pk) {
    int e = blockIdx.x * 256 + threadIdx.x;
    if (e < NE) {
        int d = ei[NE + e];
        u64 add = (1ULL << 48) | (u64)(ew[e] * 4294967296.0);
        atomicAdd(&pk[d], add);
    }
}
__global__ void k_scan1(const u64* __restrict__ pk, int* __restrict__ incl,
                        int* __restrict__ bsum) {
    __shared__ int sm[1024];
    int t = threadIdx.x, idx = blockIdx.x * 1024 + t;
    int v = (idx < NN) ? (int)(pk[idx] >> 48) : 0;
    sm[t] = v; __syncthreads();
    for (int off = 1; off < 1024; off <<= 1) {
        int add = (t >= off) ? sm[t - off] : 0;
        __syncthreads();
        sm[t] += add;
        __syncthreads();
    }
    if (idx < NN) incl[idx] = sm[t];
    if (t == 1023) bsum[blockIdx.x] = sm[t];
}
// rowptr/cursor/dis; block-sum prefix computed in-wave
__global__ void k_scan3(const int* __restrict__ incl, const u64* __restrict__ pk,
                        const int* __restrict__ bsum,
                        int* __restrict__ rowptr, int* __restrict__ cursor,
                        float* __restrict__ dis) {
    int seg = blockIdx.x >> 2;
    int lane = threadIdx.x & 63;
    int v = (lane < seg) ? bsum[lane] : 0;  // seg <= 48 < 64
    #pragma unroll
    for (int off = 32; off > 0; off >>= 1) v += __shfl_down(v, off, 64);
    int boffv = __shfl(v, 0, 64);
    int idx = blockIdx.x * 256 + threadIdx.x;
    if (idx < NN) {
        u64 p = pk[idx];
        int cnt = (int)(p >> 48);
        float deg = (float)((double)(p & 0xFFFFFFFFFFFFULL) * 2.3283064365386963e-10);
        int rp = incl[idx] - cnt + boffv;
        rowptr[idx] = rp;
        cursor[idx] = rp;
        dis[idx] = rsqrtf(1.0f + deg);
    } else if (idx == NN) {
        rowptr[NN] = NE;
    }
}
// fill CSR; dis[src] folded into weight
__global__ void k_fill(const int* __restrict__ ei, const float* __restrict__ ew,
                       const float* __restrict__ dis,
                       int* __restrict__ cursor, int2* __restrict__ meta) {
    int e = blockIdx.x * 256 + threadIdx.x;
    if (e < NE) {
        int s = ei[e];
        int d = ei[NE + e];
        int slot = atomicAdd(&cursor[d], 1);
        meta[slot] = make_int2(s, __float_as_int(ew[e] * dis[s]));
    }
}

// ======== GEMM1a (fast path): pure-async m97-style 128x128, fused epilogue ====
// Both operands bf16 via global_load_lds; XOR-swizzled LDS (conflicts 0);
// XCD swizzle: 8 n-siblings of an m-band get ids == same mod 8.
// __launch_bounds__(256, 4): force total VGPR+AGPR <= 128/wave so 4 blocks/CU
// fit (prev (256,2) left ~150 total -> 12 waves/CU; LDS 32KB allows 4-5 blocks).
__global__ __launch_bounds__(256, 4) void k_gemm1a(
    const u16* __restrict__ Abf, const u16* __restrict__ Bt, u16* __restrict__ Cout,
    const float* __restrict__ xv, const float* __restrict__ cv,
    const float* __restrict__ Wa, const float* __restrict__ Wc,
    const float* __restrict__ bl) {
    __shared__ u16 lA[128 * 64];
    __shared__ u16 lB[128 * 64];
    const int tid = threadIdx.x;
    const int lane = tid & 63, wv = tid >> 6;
    int x = blockIdx.x & 7, j = blockIdx.x >> 3;
    int bx = (j & ~7) | x;
    int by = j & 7;
    if (bx >= 391) return;  // uniform, before any barrier
    const int m0 = bx * 128, n0 = by * 128;
    const int wm = (wv >> 1) * 64, wn = (wv & 1) * 64;
    const int fr = lane & 15, qd = lane >> 4;

    f32x4 acc[4][4] = {};

    for (int kt = 0; kt < 16; kt++) {
        const int k0 = kt << 6;
        __syncthreads();
        #pragma unroll
        for (int i = 0; i < 4; i++) {
            int r0 = i * 32 + wv * 8;
            int rl = r0 + (lane >> 3);
            int slot = lane & 7;
            int k8 = slot ^ (rl & 7);
            const u16* g = Bt + (size_t)(n0 + rl) * LM + k0 + k8 * 8;
            async_copy16(&lB[r0 * 64], g);
        }
        #pragma unroll
        for (int i = 0; i < 4; i++) {
            int r0 = i * 32 + wv * 8;
            int rl = r0 + (lane >> 3);
            int slot = lane & 7;
            int k8 = slot ^ (rl & 7);
            int row = m0 + rl; if (row >= NN) row = NN - 1;
            const u16* g = Abf + (size_t)row * LM + k0 + k8 * 8;
            async_copy16(&lA[r0 * 64], g);
        }
        __syncthreads();
        #pragma unroll
        for (int s = 0; s < 2; s++) {
            const int slot = (s * 4 + qd) ^ (fr & 7);
            bf16x8 af[4], bfm[4];
            #pragma unroll
            for (int mi = 0; mi < 4; mi++)
                af[mi] = *(const bf16x8*)&lA[(wm + mi * 16 + fr) * 64 + slot * 8];
            #pragma unroll
            for (int ni = 0; ni < 4; ni++)
                bfm[ni] = *(const bf16x8*)&lB[(wn + ni * 16 + fr) * 64 + slot * 8];
            #pragma unroll
            for (int mi = 0; mi < 4; mi++)
                #pragma unroll
                for (int ni = 0; ni < 4; ni++)
                    acc[mi][ni] = __builtin_amdgcn_mfma_f32_16x16x32_bf16(
                        af[mi], bfm[ni], acc[mi][ni], 0, 0, 0);
        }
    }

    int jj[4]; float waj[4], wcj[4], blj[4];
    #pragma unroll
    for (int ni = 0; ni < 4; ni++) {
        jj[ni] = n0 + wn + ni * 16 + fr;
        waj[ni] = Wa[jj[ni]]; wcj[ni] = Wc[jj[ni]]; blj[ni] = bl[jj[ni]];
    }
    #pragma unroll
    for (int mi = 0; mi < 4; mi++)
        #pragma unroll
        for (int r = 0; r < 4; r++) {
            int row = m0 + wm + mi * 16 + qd * 4 + r;
            if (row < NN) {
                float xb = xv[row], cb = cv[row];
                #pragma unroll
                for (int ni = 0; ni < 4; ni++) {
                    float v = acc[mi][ni][r] + xb * waj[ni] + cb * wcj[ni] + blj[ni];
                    Cout[(size_t)row * LM + jj[ni]] = f2bf(fmaxf(v, 0.f));
                }
            }
        }
}

// ======== GEMM1f (fallback): 128x256 tile, fp32 A reg-prefetch staging ========
__global__ __launch_bounds__(256, 2) void k_gemm1f(
    const float* __restrict__ A32, const u16* __restrict__ Bt, u16* __restrict__ Cout,
    const float* __restrict__ xv, const float* __restrict__ cv,
    const float* __restrict__ Wa, const float* __restrict__ Wc,
    const float* __restrict__ bl) {
    __shared__ u16 lA[128 * 64];
    __shared__ u16 lB[2][128 * 64];
    const int tid = threadIdx.x;
    const int lane = tid & 63, wv = tid >> 6;
    const int bx = ((blockIdx.x >> 5) << 3) | (blockIdx.x & 7);
    const int by = (blockIdx.x >> 3) & 3;
    if (bx >= 391) return;
    const int m0 = bx * 128, n0 = by * 256;
    const int wm = (wv >> 1) * 64, wn = (wv & 1) * 64;
    const int fr = lane & 15, qd = lane >> 4;

    f32x4 acc[2][4][4] = {};

    int srl[4], sslot[4]; const float* sbase[4];
    float4 pf[8];
    #pragma unroll
    for (int i = 0; i < 4; i++) {
        int cidx = i * 256 + tid;
        srl[i] = cidx >> 3; sslot[i] = cidx & 7;
        int k8 = sslot[i] ^ (srl[i] & 7);
        int row = m0 + srl[i]; if (row >= NN) row = NN - 1;
        sbase[i] = A32 + (size_t)row * LM + k8 * 8;
    }
    #pragma unroll
    for (int i = 0; i < 4; i++) {
        pf[2 * i]     = *(const float4*)(sbase[i]);
        pf[2 * i + 1] = *(const float4*)(sbase[i] + 4);
    }

    for (int kt = 0; kt < 16; kt++) {
        const int k0 = kt << 6;
        __syncthreads();
        #pragma unroll
        for (int h = 0; h < 2; h++)
            #pragma unroll
            for (int i = 0; i < 4; i++) {
                int r0 = i * 32 + wv * 8;
                int rl = r0 + (lane >> 3);
                int slot = lane & 7;
                int k8 = slot ^ (rl & 7);
                const u16* g = Bt + (size_t)(n0 + h * 128 + rl) * LM + k0 + k8 * 8;
                async_copy16(&lB[h][r0 * 64], g);
            }
        #pragma unroll
        for (int i = 0; i < 4; i++) {
            union { ushort2 u2[4]; bf16x8 v; } pk;
            pk.u2[0] = pkbf(pf[2 * i].x, pf[2 * i].y);
            pk.u2[1] = pkbf(pf[2 * i].z, pf[2 * i].w);
            pk.u2[2] = pkbf(pf[2 * i + 1].x, pf[2 * i + 1].y);
            pk.u2[3] = pkbf(pf[2 * i + 1].z, pf[2 * i + 1].w);
            *(bf16x8*)&lA[srl[i] * 64 + sslot[i] * 8] = pk.v;
        }
        __syncthreads();
        if (kt < 15) {
            #pragma unroll
            for (int i = 0; i < 4; i++) {
                pf[2 * i]     = *(const float4*)(sbase[i] + k0 + 64);
                pf[2 * i + 1] = *(const float4*)(sbase[i] + k0 + 68);
            }
        }
        #pragma unroll
        for (int s = 0; s < 2; s++) {
            const int slot = (s * 4 + qd) ^ (fr & 7);
            bf16x8 af[4];
            #pragma unroll
            for (int mi = 0; mi < 4; mi++)
                af[mi] = *(const bf16x8*)&lA[(wm + mi * 16 + fr) * 64 + slot * 8];
            #pragma unroll
            for (int h = 0; h < 2; h++) {
                bf16x8 bfm[4];
                #pragma unroll
                for (int ni = 0; ni < 4; ni++)
                    bfm[ni] = *(const bf16x8*)&lB[h][(wn + ni * 16 + fr) * 64 + slot * 8];
                #pragma unroll
                for (int mi = 0; mi < 4; mi++)
                    #pragma unroll
                    for (int ni = 0; ni < 4; ni++)
                        acc[h][mi][ni] = __builtin_amdgcn_mfma_f32_16x16x32_bf16(
                            af[mi], bfm[ni], acc[h][mi][ni], 0, 0, 0);
            }
        }
    }

    #pragma unroll
    for (int h = 0; h < 2; h++) {
        int jj[4]; float waj[4], wcj[4], blj[4];
        #pragma unroll
        for (int ni = 0; ni < 4; ni++) {
            jj[ni] = n0 + h * 128 + wn + ni * 16 + fr;
            waj[ni] = Wa[jj[ni]]; wcj[ni] = Wc[jj[ni]]; blj[ni] = bl[jj[ni]];
        }
        #pragma unroll
        for (int mi = 0; mi < 4; mi++)
            #pragma unroll
            for (int r = 0; r < 4; r++) {
                int row = m0 + wm + mi * 16 + qd * 4 + r;
                if (row < NN) {
                    float xb = xv[row], cb = cv[row];
                    #pragma unroll
                    for (int ni = 0; ni < 4; ni++) {
                        float v = acc[h][mi][ni][r] + xb * waj[ni] + cb * wcj[ni] + blj[ni];
                        Cout[(size_t)row * LM + jj[ni]] = f2bf(fmaxf(v, 0.f));
                    }
                }
            }
    }
}

// ======== GEMM2: y1 = h @ W1, 64x128 tile ========
__global__ __launch_bounds__(256) void k_gemm2(
    const u16* __restrict__ Abf, const u16* __restrict__ Bt, u16* __restrict__ Cout) {
    __shared__ u16 lA[64 * 64];
    __shared__ u16 lB[128 * 64];
    const int tid = threadIdx.x;
    const int lane = tid & 63, wv = tid >> 6;
    const int m0 = blockIdx.x * 64;
    const int wm = (wv >> 1) * 32, wn = (wv & 1) * 64;
    const int fr = lane & 15, qd = lane >> 4;
    f32x4 acc[2][4] = {};

    for (int kt = 0; kt < 16; kt++) {
        const int k0 = kt << 6;
        __syncthreads();
        #pragma unroll
        for (int i = 0; i < 4; i++) {
            int r0 = i * 32 + wv * 8;
            int rl = r0 + (lane >> 3);
            int slot = lane & 7;
            int k8 = slot ^ (rl & 7);
            const u16* g = Bt + (size_t)rl * LM + k0 + k8 * 8;
            async_copy16(&lB[r0 * 64], g);
        }
        #pragma unroll
        for (int i = 0; i < 2; i++) {
            int r0 = i * 32 + wv * 8;
            int rl = r0 + (lane >> 3);
            int slot = lane & 7;
            int k8 = slot ^ (rl & 7);
            int row = m0 + rl; if (row >= NN) row = NN - 1;
            const u16* g = Abf + (size_t)row * LM + k0 + k8 * 8;
            async_copy16(&lA[r0 * 64], g);
        }
        __syncthreads();
        #pragma unroll
        for (int s = 0; s < 2; s++) {
            const int slot = (s * 4 + qd) ^ (fr & 7);
            bf16x8 af[2], bfm[4];
            #pragma unroll
            for (int mi = 0; mi < 2; mi++)
                af[mi] = *(const bf16x8*)&lA[(wm + mi * 16 + fr) * 64 + slot * 8];
            #pragma unroll
            for (int ni = 0; ni < 4; ni++)
                bfm[ni] = *(const bf16x8*)&lB[(wn + ni * 16 + fr) * 64 + slot * 8];
            #pragma unroll
            for (int mi = 0; mi < 2; mi++)
                #pragma unroll
                for (int ni = 0; ni < 4; ni++)
                    acc[mi][ni] = __builtin_amdgcn_mfma_f32_16x16x32_bf16(
                        af[mi], bfm[ni], acc[mi][ni], 0, 0, 0);
        }
    }
    #pragma unroll
    for (int mi = 0; mi < 2; mi++)
        #pragma unroll
        for (int r = 0; r < 4; r++) {
            int row = m0 + wm + mi * 16 + qd * 4 + r;
            if (row < NN) {
                #pragma unroll
                for (int ni = 0; ni < 4; ni++)
                    Cout[(size_t)row * HC + wn + ni * 16 + fr] = f2bf(acc[mi][ni][r]);
            }
        }
}

// ====== fused agg1 + gemm3 ======
__global__ __launch_bounds__(512) void k_agg1g3(
    const u16* __restrict__ y1, const int* __restrict__ rowptr,
    const int2* __restrict__ meta, const float* __restrict__ dis,
    const float* __restrict__ b1, const float* __restrict__ W3,
    u16* __restrict__ y3) {
    __shared__ float hrow[8][HC];
    int wv = threadIdx.x >> 6, lane = threadIdx.x & 63;
    int node = blockIdx.x * 8 + wv;
    if (node >= NN) return;
    float di = dis[node];
    int p0 = rowptr[node], p1 = rowptr[node + 1];
    ushort2 sv = *(const ushort2*)(y1 + (size_t)node * HC + lane * 2);
    float a0 = di * bf2f(sv.x), a1 = di * bf2f(sv.y);
    #pragma unroll 8
    for (int p = p0; p < p1; ++p) {
        int2 m = meta[p];
        float nm = __int_as_float(m.y);
        ushort2 v = *(const ushort2*)(y1 + (size_t)m.x * HC + lane * 2);
        a0 += nm * bf2f(v.x);
        a1 += nm * bf2f(v.y);
    }
    a0 = fmaxf(di * a0 + b1[lane * 2], 0.f);
    a1 = fmaxf(di * a1 + b1[lane * 2 + 1], 0.f);
    hrow[wv][lane * 2] = a0;
    hrow[wv][lane * 2 + 1] = a1;
    float acc = 0.f;
    #pragma unroll 8
    for (int k = 0; k < HC; ++k)
        acc += hrow[wv][k] * W3[(size_t)k * OC + lane];
    y3[(size_t)node * OC + lane] = f2bf(acc);
}

// ================= aggregation 3 =================
__global__ __launch_bounds__(256) void k_agg3(
    const u16* __restrict__ y3, const int* __restrict__ rowptr,
    const int2* __restrict__ meta, const float* __restrict__ dis,
    const float* __restrict__ b3, float* __restrict__ outp) {
    int node = blockIdx.x * 4 + (threadIdx.x >> 6);
    int lane = threadIdx.x & 63;
    if (node >= NN) return;
    float di = dis[node];
    int p0 = rowptr[node], p1 = rowptr[node + 1];
    float a = di * bf2f(y3[(size_t)node * OC + lane]);
    #pragma unroll 8
    for (int p = p0; p < p1; ++p) {
        int2 m = meta[p];
        a += __int_as_float(m.y) * bf2f(y3[(size_t)m.x * OC + lane]);
    }
    outp[(size_t)node * OC + lane] = di * a + b3[lane];
}

extern "C" void kernel_launch(void* const* d_in, const int* in_sizes, int n_in,
                              void* d_out, int out_size, void* d_ws, size_t ws_size,
                              hipStream_t stream) {
    const float* x    = (const float*)d_in[0];
    const float* xout = (const float*)d_in[1];
    const float* c    = (const float*)d_in[2];
    const int*   ei   = (const int*)d_in[3];
    const float* ew   = (const float*)d_in[4];
    const float* Wa   = (const float*)d_in[5];
    const float* Wc   = (const float*)d_in[6];
    const float* Wl   = (const float*)d_in[7];
    const float* bl   = (const float*)d_in[8];
    const float* W1   = (const float*)d_in[9];
    const float* b1   = (const float*)d_in[10];
    const float* W3   = (const float*)d_in[11];
    const float* b3   = (const float*)d_in[12];
    float* outp = (float*)d_out;

    char* ws = (char*)d_ws;
    int*   rowptr = (int*)(ws + OFF_ROWPTR);
    int*   cursor = (int*)(ws + OFF_CURSOR);
    u64*   pk     = (u64*)(ws + OFF_PK);
    int*   incl   = (int*)(ws + OFF_INCL);
    int*   bsum   = (int*)(ws + OFF_BSUM);
    float* dis    = (float*)(ws + OFF_DIS);
    int2*  meta   = (int2*)(ws + OFF_META);
    u16*   WlT    = (u16*)(ws + OFF_WLT);
    u16*   W1T    = (u16*)(ws + OFF_W1T);
    u16*   hbuf   = (u16*)(ws + OFF_H);
    u16*   y1     = (u16*)(ws + OFF_Y1);
    u16*   y3     = (u16*)(ws + OFF_Y3);
    u16*   Abf    = (u16*)(ws + OFF_ABF);

    const bool fast = (ws_size >= NEED_FAST);

    // setup: zero pk + weight converts (+ x_out bf16 convert when fast path)
    k_setup<<<fast ? 26732 : 1732, 256, 0, stream>>>(pk, Wl, WlT, W1, W1T, xout, Abf);
    k_count<<<3125, 256, 0, stream>>>(ei, ew, pk);
    k_scan1<<<49, 1024, 0, stream>>>(pk, incl, bsum);
    k_scan3<<<196, 256, 0, stream>>>(incl, pk, bsum, rowptr, cursor, dis);
    k_fill <<<3125, 256, 0, stream>>>(ei, ew, dis, cursor, meta);

    if (fast) {
        k_gemm1a<<<392 * 8, 256, 0, stream>>>(Abf, WlT, hbuf, x, c, Wa, Wc, bl);
    } else {
        k_gemm1f<<<49 * 32, 256, 0, stream>>>(xout, WlT, hbuf, x, c, Wa, Wc, bl);
    }
    // GEMM2: y1 = h @ W1
    k_gemm2<<<782, 256, 0, stream>>>(hbuf, W1T, y1);
    // conv1 aggregation + bias + relu + conv3 linear (fused)
    k_agg1g3<<<6250, 512, 0, stream>>>(y1, rowptr, meta, dis, b1, W3, y3);
    // conv3 aggregation + bias -> out
    k_agg3<<<12500, 256, 0, stream>>>(y3, rowptr, meta, dis, b3, outp);
}

// Round 4
// 647.537 us; speedup vs baseline: 1.1572x; 1.0250x over previous
//
#include <hip/hip_runtime.h>
#include <hip/hip_bf16.h>

typedef unsigned short u16;
typedef unsigned long long u64;
typedef __attribute__((ext_vector_type(8))) short bf16x8;
typedef __attribute__((ext_vector_type(4))) float f32x4;

constexpr int NN = 50000;   // nodes
constexpr int NE = 800000;  // edges
constexpr int LM = 1024;
constexpr int HC = 128;
constexpr int OC = 64;

// ---- workspace layout (bytes) ----
constexpr size_t OFF_ROWPTR = 0;          // (NN+1) int
constexpr size_t OFF_CURSOR = 200192;     // NN int
constexpr size_t OFF_PK     = 400384;     // NN u64 (count<<48 | fx32 weight sum)
constexpr size_t OFF_INCL   = 800512;     // NN int
constexpr size_t OFF_BSUM   = 1000704;    // 64 int
constexpr size_t OFF_DIS    = 1000960;    // NN float
constexpr size_t OFF_META   = 1201152;    // NE int2 (src, w-bits)
constexpr size_t OFF_WLT    = 7601408;    // LM*LM u16
constexpr size_t OFF_W1T    = 9698560;    // HC*LM u16
constexpr size_t OFF_H      = 9960704;    // NN*LM u16
constexpr size_t OFF_Y1     = 112360704;  // NN*HC u16
constexpr size_t OFF_Y3     = 125160704;  // NN*OC u16
constexpr size_t OFF_ABF    = 131560704;  // NN*LM u16 (fast path only)
constexpr size_t NEED_FAST  = OFF_ABF + (size_t)NN * LM * 2;  // ~234 MB

// Abf convert chunk partition (each chunk = 8 elems; total NN*LM/8 = 6.4M)
constexpr size_t CVT_TOTAL = (size_t)NN * LM / 8;        // 6,400,000
constexpr size_t CVT_CNT   = 2560000;  // in k_count  (10000 blk x 256)
constexpr size_t CVT_SC1   = 1280000;  // in k_scan1  (1250 blk x 1024)
constexpr size_t CVT_SC3   = 640000;   // in k_scan3  (2500 blk x 256)
constexpr size_t CVT_FIL   = 1920000;  // in k_fill   (7500 blk x 256)

__device__ __forceinline__ u16 f2bf(float f) {
    union { float f; unsigned int u; } a; a.f = f;
    unsigned int u = a.u + 0x7FFFu + ((a.u >> 16) & 1u);  // RNE
    return (u16)(u >> 16);
}
__device__ __forceinline__ float bf2f(u16 v) {
    union { unsigned int u; float f; } a; a.u = ((unsigned int)v) << 16;
    return a.f;
}
__device__ __forceinline__ ushort2 pkbf(float a, float b) {
    union { __hip_bfloat162 h; ushort2 u; } cv;
    cv.h = __float22bfloat162_rn(make_float2(a, b));
    return cv.u;
}
__device__ __forceinline__ void async_copy16(u16* lds, const u16* g) {
    __builtin_amdgcn_global_load_lds(
        (const __attribute__((address_space(1))) void*)g,
        (__attribute__((address_space(3))) void*)lds, 16, 0, 0);
}
// one chunk = 8 fp32 -> 8 bf16
__device__ __forceinline__ void cvt_chunk(size_t idx, const float* __restrict__ A32,
                                          u16* __restrict__ Abf) {
    const float* src = A32 + idx * 8;
    float4 v0 = *(const float4*)(src);
    float4 v1 = *(const float4*)(src + 4);
    union { ushort2 u2[4]; bf16x8 v; } pk2;
    pk2.u2[0] = pkbf(v0.x, v0.y);
    pk2.u2[1] = pkbf(v0.z, v0.w);
    pk2.u2[2] = pkbf(v1.x, v1.y);
    pk2.u2[3] = pkbf(v1.z, v1.w);
    *(bf16x8*)(Abf + idx * 8) = pk2.v;
}

// ================= zero pk (must precede k_count's atomics) =================
__global__ void k_zero(u64* __restrict__ pk) {
    int i = blockIdx.x * 256 + threadIdx.x;
    if (i < NN) pk[i] = 0ULL;
}

// ====== k_count: edge-count atomics + Wl/W1 converts + Abf chunk share ======
// blocks [0,3125): edge atomics; [3125,4149): WlT transpose; [4149,4661): W1T;
// [4661,14661) fast path: Abf chunks [0, 2.56M).
__global__ void k_count(const int* __restrict__ ei, const float* __restrict__ ew,
                        u64* __restrict__ pk,
                        const float* __restrict__ Wl, u16* __restrict__ WlT,
                        const float* __restrict__ W1, u16* __restrict__ W1T,
                        const float* __restrict__ A32, u16* __restrict__ Abf) {
    int b = blockIdx.x, t = threadIdx.x;
    if (b < 3125) {
        int e = b * 256 + t;
        if (e < NE) {
            int d = ei[NE + e];
            u64 add = (1ULL << 48) | (u64)(ew[e] * 4294967296.0);
            atomicAdd(&pk[d], add);
        }
    } else if (b < 4149) {
        __shared__ float sm[32][33];
        int bb = b - 3125;
        int n0 = (bb & 31) * 32, k0 = (bb >> 5) * 32;
        int ty = t >> 5, tx = t & 31;
        #pragma unroll
        for (int i = 0; i < 4; i++)
            sm[ty + i * 8][tx] = Wl[(size_t)(k0 + ty + i * 8) * LM + n0 + tx];
        __syncthreads();
        #pragma unroll
        for (int i = 0; i < 4; i++)
            WlT[(size_t)(n0 + ty + i * 8) * LM + k0 + tx] = f2bf(sm[tx][ty + i * 8]);
    } else if (b < 4661) {
        int idx = (b - 4149) * 256 + t;  // HC*LM, output-major
        if (idx < HC * LM) {
            int o = idx >> 10, k = idx & 1023;
            W1T[idx] = f2bf(W1[(size_t)k * HC + o]);
        }
    } else {
        cvt_chunk((size_t)(b - 4661) * 256 + t, A32, Abf);
    }
}

// ====== scan1 (+ Abf chunk share [2.56M, 3.84M)) ======
__global__ void k_scan1(const u64* __restrict__ pk, int* __restrict__ incl,
                        int* __restrict__ bsum,
                        const float* __restrict__ A32, u16* __restrict__ Abf) {
    int b = blockIdx.x, t = threadIdx.x;
    if (b >= 49) {
        cvt_chunk(CVT_CNT + (size_t)(b - 49) * 1024 + t, A32, Abf);
        return;
    }
    __shared__ int sm[1024];
    int idx = b * 1024 + t;
    int v = (idx < NN) ? (int)(pk[idx] >> 48) : 0;
    sm[t] = v; __syncthreads();
    for (int off = 1; off < 1024; off <<= 1) {
        int add = (t >= off) ? sm[t - off] : 0;
        __syncthreads();
        sm[t] += add;
        __syncthreads();
    }
    if (idx < NN) incl[idx] = sm[t];
    if (t == 1023) bsum[b] = sm[t];
}

// ====== scan3: rowptr/cursor/dis (+ Abf chunk share [3.84M, 4.48M)) ======
__global__ void k_scan3(const int* __restrict__ incl, const u64* __restrict__ pk,
                        const int* __restrict__ bsum,
                        int* __restrict__ rowptr, int* __restrict__ cursor,
                        float* __restrict__ dis,
                        const float* __restrict__ A32, u16* __restrict__ Abf) {
    int b = blockIdx.x;
    if (b >= 196) {
        cvt_chunk(CVT_CNT + CVT_SC1 + (size_t)(b - 196) * 256 + threadIdx.x, A32, Abf);
        return;
    }
    int seg = b >> 2;
    int lane = threadIdx.x & 63;
    int v = (lane < seg) ? bsum[lane] : 0;  // seg <= 48 < 64
    #pragma unroll
    for (int off = 32; off > 0; off >>= 1) v += __shfl_down(v, off, 64);
    int boffv = __shfl(v, 0, 64);
    int idx = b * 256 + threadIdx.x;
    if (idx < NN) {
        u64 p = pk[idx];
        int cnt = (int)(p >> 48);
        float deg = (float)((double)(p & 0xFFFFFFFFFFFFULL) * 2.3283064365386963e-10);
        int rp = incl[idx] - cnt + boffv;
        rowptr[idx] = rp;
        cursor[idx] = rp;
        dis[idx] = rsqrtf(1.0f + deg);
    } else if (idx == NN) {
        rowptr[NN] = NE;
    }
}

// ====== fill CSR; dis[src] folded into weight (+ Abf chunks [4.48M, 6.4M)) ===
__global__ void k_fill(const int* __restrict__ ei, const float* __restrict__ ew,
                       const float* __restrict__ dis,
                       int* __restrict__ cursor, int2* __restrict__ meta,
                       const float* __restrict__ A32, u16* __restrict__ Abf) {
    int b = blockIdx.x;
    if (b >= 3125) {
        cvt_chunk(CVT_CNT + CVT_SC1 + CVT_SC3 + (size_t)(b - 3125) * 256 + threadIdx.x,
                  A32, Abf);
        return;
    }
    int e = b * 256 + threadIdx.x;
    if (e < NE) {
        int s = ei[e];
        int d = ei[NE + e];
        int slot = atomicAdd(&cursor[d], 1);
        meta[slot] = make_int2(s, __float_as_int(ew[e] * dis[s]));
    }
}

// ======== GEMM1a (fast path): pure-async m97-style 128x128, fused epilogue ====
// Both operands bf16 via global_load_lds; XOR-swizzled LDS (conflicts 0);
// XCD swizzle: 8 n-siblings of an m-band get ids == same mod 8.
// (256,2): r3 showed (256,4) is a ~5% regression, occupancy unchanged -> revert.
__global__ __launch_bounds__(256, 2) void k_gemm1a(
    const u16* __restrict__ Abf, const u16* __restrict__ Bt, u16* __restrict__ Cout,
    const float* __restrict__ xv, const float* __restrict__ cv,
    const float* __restrict__ Wa, const float* __restrict__ Wc,
    const float* __restrict__ bl) {
    __shared__ u16 lA[128 * 64];
    __shared__ u16 lB[128 * 64];
    const int tid = threadIdx.x;
    const int lane = tid & 63, wv = tid >> 6;
    int x = blockIdx.x & 7, j = blockIdx.x >> 3;
    int bx = (j & ~7) | x;
    int by = j & 7;
    if (bx >= 391) return;  // uniform, before any barrier
    const int m0 = bx * 128, n0 = by * 128;
    const int wm = (wv >> 1) * 64, wn = (wv & 1) * 64;
    const int fr = lane & 15, qd = lane >> 4;

    f32x4 acc[4][4] = {};

    for (int kt = 0; kt < 16; kt++) {
        const int k0 = kt << 6;
        __syncthreads();
        #pragma unroll
        for (int i = 0; i < 4; i++) {
            int r0 = i * 32 + wv * 8;
            int rl = r0 + (lane >> 3);
            int slot = lane & 7;
            int k8 = slot ^ (rl & 7);
            const u16* g = Bt + (size_t)(n0 + rl) * LM + k0 + k8 * 8;
            async_copy16(&lB[r0 * 64], g);
        }
        #pragma unroll
        for (int i = 0; i < 4; i++) {
            int r0 = i * 32 + wv * 8;
            int rl = r0 + (lane >> 3);
            int slot = lane & 7;
            int k8 = slot ^ (rl & 7);
            int row = m0 + rl; if (row >= NN) row = NN - 1;
            const u16* g = Abf + (size_t)row * LM + k0 + k8 * 8;
            async_copy16(&lA[r0 * 64], g);
        }
        __syncthreads();
        #pragma unroll
        for (int s = 0; s < 2; s++) {
            const int slot = (s * 4 + qd) ^ (fr & 7);
            bf16x8 af[4], bfm[4];
            #pragma unroll
            for (int mi = 0; mi < 4; mi++)
                af[mi] = *(const bf16x8*)&lA[(wm + mi * 16 + fr) * 64 + slot * 8];
            #pragma unroll
            for (int ni = 0; ni < 4; ni++)
                bfm[ni] = *(const bf16x8*)&lB[(wn + ni * 16 + fr) * 64 + slot * 8];
            #pragma unroll
            for (int mi = 0; mi < 4; mi++)
                #pragma unroll
                for (int ni = 0; ni < 4; ni++)
                    acc[mi][ni] = __builtin_amdgcn_mfma_f32_16x16x32_bf16(
                        af[mi], bfm[ni], acc[mi][ni], 0, 0, 0);
        }
    }

    int jj[4]; float waj[4], wcj[4], blj[4];
    #pragma unroll
    for (int ni = 0; ni < 4; ni++) {
        jj[ni] = n0 + wn + ni * 16 + fr;
        waj[ni] = Wa[jj[ni]]; wcj[ni] = Wc[jj[ni]]; blj[ni] = bl[jj[ni]];
    }
    #pragma unroll
    for (int mi = 0; mi < 4; mi++)
        #pragma unroll
        for (int r = 0; r < 4; r++) {
            int row = m0 + wm + mi * 16 + qd * 4 + r;
            if (row < NN) {
                float xb = xv[row], cb = cv[row];
                #pragma unroll
                for (int ni = 0; ni < 4; ni++) {
                    float v = acc[mi][ni][r] + xb * waj[ni] + cb * wcj[ni] + blj[ni];
                    Cout[(size_t)row * LM + jj[ni]] = f2bf(fmaxf(v, 0.f));
                }
            }
        }
}

// ======== GEMM1f (fallback): 128x256 tile, fp32 A reg-prefetch staging ========
__global__ __launch_bounds__(256, 2) void k_gemm1f(
    const float* __restrict__ A32, const u16* __restrict__ Bt, u16* __restrict__ Cout,
    const float* __restrict__ xv, const float* __restrict__ cv,
    const float* __restrict__ Wa, const float* __restrict__ Wc,
    const float* __restrict__ bl) {
    __shared__ u16 lA[128 * 64];
    __shared__ u16 lB[2][128 * 64];
    const int tid = threadIdx.x;
    const int lane = tid & 63, wv = tid >> 6;
    const int bx = ((blockIdx.x >> 5) << 3) | (blockIdx.x & 7);
    const int by = (blockIdx.x >> 3) & 3;
    if (bx >= 391) return;
    const int m0 = bx * 128, n0 = by * 256;
    const int wm = (wv >> 1) * 64, wn = (wv & 1) * 64;
    const int fr = lane & 15, qd = lane >> 4;

    f32x4 acc[2][4][4] = {};

    int srl[4], sslot[4]; const float* sbase[4];
    float4 pf[8];
    #pragma unroll
    for (int i = 0; i < 4; i++) {
        int cidx = i * 256 + tid;
        srl[i] = cidx >> 3; sslot[i] = cidx & 7;
        int k8 = sslot[i] ^ (srl[i] & 7);
        int row = m0 + srl[i]; if (row >= NN) row = NN - 1;
        sbase[i] = A32 + (size_t)row * LM + k8 * 8;
    }
    #pragma unroll
    for (int i = 0; i < 4; i++) {
        pf[2 * i]     = *(const float4*)(sbase[i]);
        pf[2 * i + 1] = *(const float4*)(sbase[i] + 4);
    }

    for (int kt = 0; kt < 16; kt++) {
        const int k0 = kt << 6;
        __syncthreads();
        #pragma unroll
        for (int h = 0; h < 2; h++)
            #pragma unroll
            for (int i = 0; i < 4; i++) {
                int r0 = i * 32 + wv * 8;
                int rl = r0 + (lane >> 3);
                int slot = lane & 7;
                int k8 = slot ^ (rl & 7);
                const u16* g = Bt + (size_t)(n0 + h * 128 + rl) * LM + k0 + k8 * 8;
                async_copy16(&lB[h][r0 * 64], g);
            }
        #pragma unroll
        for (int i = 0; i < 4; i++) {
            union { ushort2 u2[4]; bf16x8 v; } pk;
            pk.u2[0] = pkbf(pf[2 * i].x, pf[2 * i].y);
            pk.u2[1] = pkbf(pf[2 * i].z, pf[2 * i].w);
            pk.u2[2] = pkbf(pf[2 * i + 1].x, pf[2 * i + 1].y);
            pk.u2[3] = pkbf(pf[2 * i + 1].z, pf[2 * i + 1].w);
            *(bf16x8*)&lA[srl[i] * 64 + sslot[i] * 8] = pk.v;
        }
        __syncthreads();
        if (kt < 15) {
            #pragma unroll
            for (int i = 0; i < 4; i++) {
                pf[2 * i]     = *(const float4*)(sbase[i] + k0 + 64);
                pf[2 * i + 1] = *(const float4*)(sbase[i] + k0 + 68);
            }
        }
        #pragma unroll
        for (int s = 0; s < 2; s++) {
            const int slot = (s * 4 + qd) ^ (fr & 7);
            bf16x8 af[4];
            #pragma unroll
            for (int mi = 0; mi < 4; mi++)
                af[mi] = *(const bf16x8*)&lA[(wm + mi * 16 + fr) * 64 + slot * 8];
            #pragma unroll
            for (int h = 0; h < 2; h++) {
                bf16x8 bfm[4];
                #pragma unroll
                for (int ni = 0; ni < 4; ni++)
                    bfm[ni] = *(const bf16x8*)&lB[h][(wn + ni * 16 + fr) * 64 + slot * 8];
                #pragma unroll
                for (int mi = 0; mi < 4; mi++)
                    #pragma unroll
                    for (int ni = 0; ni < 4; ni++)
                        acc[h][mi][ni] = __builtin_amdgcn_mfma_f32_16x16x32_bf16(
                            af[mi], bfm[ni], acc[h][mi][ni], 0, 0, 0);
            }
        }
    }

    #pragma unroll
    for (int h = 0; h < 2; h++) {
        int jj[4]; float waj[4], wcj[4], blj[4];
        #pragma unroll
        for (int ni = 0; ni < 4; ni++) {
            jj[ni] = n0 + h * 128 + wn + ni * 16 + fr;
            waj[ni] = Wa[jj[ni]]; wcj[ni] = Wc[jj[ni]]; blj[ni] = bl[jj[ni]];
        }
        #pragma unroll
        for (int mi = 0; mi < 4; mi++)
            #pragma unroll
            for (int r = 0; r < 4; r++) {
                int row = m0 + wm + mi * 16 + qd * 4 + r;
                if (row < NN) {
                    float xb = xv[row], cb = cv[row];
                    #pragma unroll
                    for (int ni = 0; ni < 4; ni++) {
                        float v = acc[h][mi][ni][r] + xb * waj[ni] + cb * wcj[ni] + blj[ni];
                        Cout[(size_t)row * LM + jj[ni]] = f2bf(fmaxf(v, 0.f));
                    }
                }
            }
    }
}

// ======== GEMM2: y1 = h @ W1, 64x128 tile ========
__global__ __launch_bounds__(256) void k_gemm2(
    const u16* __restrict__ Abf, const u16* __restrict__ Bt, u16* __restrict__ Cout) {
    __shared__ u16 lA[64 * 64];
    __shared__ u16 lB[128 * 64];
    const int tid = threadIdx.x;
    const int lane = tid & 63, wv = tid >> 6;
    const int m0 = blockIdx.x * 64;
    const int wm = (wv >> 1) * 32, wn = (wv & 1) * 64;
    const int fr = lane & 15, qd = lane >> 4;
    f32x4 acc[2][4] = {};

    for (int kt = 0; kt < 16; kt++) {
        const int k0 = kt << 6;
        __syncthreads();
        #pragma unroll
        for (int i = 0; i < 4; i++) {
            int r0 = i * 32 + wv * 8;
            int rl = r0 + (lane >> 3);
            int slot = lane & 7;
            int k8 = slot ^ (rl & 7);
            const u16* g = Bt + (size_t)rl * LM + k0 + k8 * 8;
            async_copy16(&lB[r0 * 64], g);
        }
        #pragma unroll
        for (int i = 0; i < 2; i++) {
            int r0 = i * 32 + wv * 8;
            int rl = r0 + (lane >> 3);
            int slot = lane & 7;
            int k8 = slot ^ (rl & 7);
            int row = m0 + rl; if (row >= NN) row = NN - 1;
            const u16* g = Abf + (size_t)row * LM + k0 + k8 * 8;
            async_copy16(&lA[r0 * 64], g);
        }
        __syncthreads();
        #pragma unroll
        for (int s = 0; s < 2; s++) {
            const int slot = (s * 4 + qd) ^ (fr & 7);
            bf16x8 af[2], bfm[4];
            #pragma unroll
            for (int mi = 0; mi < 2; mi++)
                af[mi] = *(const bf16x8*)&lA[(wm + mi * 16 + fr) * 64 + slot * 8];
            #pragma unroll
            for (int ni = 0; ni < 4; ni++)
                bfm[ni] = *(const bf16x8*)&lB[(wn + ni * 16 + fr) * 64 + slot * 8];
            #pragma unroll
            for (int mi = 0; mi < 2; mi++)
                #pragma unroll
                for (int ni = 0; ni < 4; ni++)
                    acc[mi][ni] = __builtin_amdgcn_mfma_f32_16x16x32_bf16(
                        af[mi], bfm[ni], acc[mi][ni], 0, 0, 0);
        }
    }
    #pragma unroll
    for (int mi = 0; mi < 2; mi++)
        #pragma unroll
        for (int r = 0; r < 4; r++) {
            int row = m0 + wm + mi * 16 + qd * 4 + r;
            if (row < NN) {
                #pragma unroll
                for (int ni = 0; ni < 4; ni++)
                    Cout[(size_t)row * HC + wn + ni * 16 + fr] = f2bf(acc[mi][ni][r]);
            }
        }
}

// ====== fused agg1 + gemm3 ======
__global__ __launch_bounds__(512) void k_agg1g3(
    const u16* __restrict__ y1, const int* __restrict__ rowptr,
    const int2* __restrict__ meta, const float* __restrict__ dis,
    const float* __restrict__ b1, const float* __restrict__ W3,
    u16* __restrict__ y3) {
    __shared__ float hrow[8][HC];
    int wv = threadIdx.x >> 6, lane = threadIdx.x & 63;
    int node = blockIdx.x * 8 + wv;
    if (node >= NN) return;
    float di = dis[node];
    int p0 = rowptr[node], p1 = rowptr[node + 1];
    ushort2 sv = *(const ushort2*)(y1 + (size_t)node * HC + lane * 2);
    float a0 = di * bf2f(sv.x), a1 = di * bf2f(sv.y);
    #pragma unroll 8
    for (int p = p0; p < p1; ++p) {
        int2 m = meta[p];
        float nm = __int_as_float(m.y);
        ushort2 v = *(const ushort2*)(y1 + (size_t)m.x * HC + lane * 2);
        a0 += nm * bf2f(v.x);
        a1 += nm * bf2f(v.y);
    }
    a0 = fmaxf(di * a0 + b1[lane * 2], 0.f);
    a1 = fmaxf(di * a1 + b1[lane * 2 + 1], 0.f);
    hrow[wv][lane * 2] = a0;
    hrow[wv][lane * 2 + 1] = a1;
    float acc = 0.f;
    #pragma unroll 8
    for (int k = 0; k < HC; ++k)
        acc += hrow[wv][k] * W3[(size_t)k * OC + lane];
    y3[(size_t)node * OC + lane] = f2bf(acc);
}

// ================= aggregation 3 =================
__global__ __launch_bounds__(256) void k_agg3(
    const u16* __restrict__ y3, const int* __restrict__ rowptr,
    const int2* __restrict__ meta, const float* __restrict__ dis,
    const float* __restrict__ b3, float* __restrict__ outp) {
    int node = blockIdx.x * 4 + (threadIdx.x >> 6);
    int lane = threadIdx.x & 63;
    if (node >= NN) return;
    float di = dis[node];
    int p0 = rowptr[node], p1 = rowptr[node + 1];
    float a = di * bf2f(y3[(size_t)node * OC + lane]);
    #pragma unroll 8
    for (int p = p0; p < p1; ++p) {
        int2 m = meta[p];
        a += __int_as_float(m.y) * bf2f(y3[(size_t)m.x * OC + lane]);
    }
    outp[(size_t)node * OC + lane] = di * a + b3[lane];
}

extern "C" void kernel_launch(void* const* d_in, const int* in_sizes, int n_in,
                              void* d_out, int out_size, void* d_ws, size_t ws_size,
                              hipStream_t stream) {
    const float* x    = (const float*)d_in[0];
    const float* xout = (const float*)d_in[1];
    const float* c    = (const float*)d_in[2];
    const int*   ei   = (const int*)d_in[3];
    const float* ew   = (const float*)d_in[4];
    const float* Wa   = (const float*)d_in[5];
    const float* Wc   = (const float*)d_in[6];
    const float* Wl   = (const float*)d_in[7];
    const float* bl   = (const float*)d_in[8];
    const float* W1   = (const float*)d_in[9];
    const float* b1   = (const float*)d_in[10];
    const float* W3   = (const float*)d_in[11];
    const float* b3   = (const float*)d_in[12];
    float* outp = (float*)d_out;

    char* ws = (char*)d_ws;
    int*   rowptr = (int*)(ws + OFF_ROWPTR);
    int*   cursor = (int*)(ws + OFF_CURSOR);
    u64*   pk     = (u64*)(ws + OFF_PK);
    int*   incl   = (int*)(ws + OFF_INCL);
    int*   bsum   = (int*)(ws + OFF_BSUM);
    float* dis    = (float*)(ws + OFF_DIS);
    int2*  meta   = (int2*)(ws + OFF_META);
    u16*   WlT    = (u16*)(ws + OFF_WLT);
    u16*   W1T    = (u16*)(ws + OFF_W1T);
    u16*   hbuf   = (u16*)(ws + OFF_H);
    u16*   y1     = (u16*)(ws + OFF_Y1);
    u16*   y3     = (u16*)(ws + OFF_Y3);
    u16*   Abf    = (u16*)(ws + OFF_ABF);

    const bool fast = (ws_size >= NEED_FAST);

    // pk zero must complete before count's atomics (separate dispatch)
    k_zero<<<196, 256, 0, stream>>>(pk);
    // CSR chain with the x_out bf16 convert riding in otherwise-idle CUs:
    // count carries Wl/W1 converts + 2.56M chunks; scan1 +1.28M; scan3 +0.64M;
    // fill +1.92M. All Abf work completes before k_gemm1a (stream order).
    k_count<<<fast ? 14661 : 4661, 256, 0, stream>>>(ei, ew, pk, Wl, WlT, W1, W1T,
                                                     xout, Abf);
    k_scan1<<<fast ? 1299 : 49, 1024, 0, stream>>>(pk, incl, bsum, xout, Abf);
    k_scan3<<<fast ? 2696 : 196, 256, 0, stream>>>(incl, pk, bsum, rowptr, cursor,
                                                   dis, xout, Abf);
    k_fill <<<fast ? 10625 : 3125, 256, 0, stream>>>(ei, ew, dis, cursor, meta,
                                                     xout, Abf);

    if (fast) {
        k_gemm1a<<<392 * 8, 256, 0, stream>>>(Abf, WlT, hbuf, x, c, Wa, Wc, bl);
    } else {
        k_gemm1f<<<49 * 32, 256, 0, stream>>>(xout, WlT, hbuf, x, c, Wa, Wc, bl);
    }
    // GEMM2: y1 = h @ W1
    k_gemm2<<<782, 256, 0, stream>>>(hbuf, W1T, y1);
    // conv1 aggregation + bias + relu + conv3 linear (fused)
    k_agg1g3<<<6250, 512, 0, stream>>>(y1, rowptr, meta, dis, b1, W3, y3);
    // conv3 aggregation + bias -> out
    k_agg3<<<12500, 256, 0, stream>>>(y3, rowptr, meta, dis, b3, outp);
}

// Round 5
// 632.575 us; speedup vs baseline: 1.1845x; 1.0237x over previous
//
#include <hip/hip_runtime.h>
#include <hip/hip_bf16.h>

typedef unsigned short u16;
typedef unsigned long long u64;
typedef __attribute__((ext_vector_type(8))) short bf16x8;
typedef __attribute__((ext_vector_type(4))) float f32x4;

constexpr int NN = 50000;   // nodes
constexpr int NE = 800000;  // edges
constexpr int LM = 1024;
constexpr int HC = 128;
constexpr int OC = 64;

// ---- workspace layout (bytes) ----
constexpr size_t OFF_ROWPTR = 0;          // (NN+1) int
constexpr size_t OFF_CURSOR = 200192;     // NN int
constexpr size_t OFF_PK     = 400384;     // NN u64 (count<<48 | fx32 weight sum)
constexpr size_t OFF_INCL   = 800512;     // NN int
constexpr size_t OFF_BSUM   = 1000704;    // 64 int
constexpr size_t OFF_DIS    = 1000960;    // NN float
constexpr size_t OFF_META   = 1201152;    // NE int2 (src, w-bits)
constexpr size_t OFF_WLT    = 7601408;    // LM*LM u16
constexpr size_t OFF_W1T    = 9698560;    // HC*LM u16
constexpr size_t OFF_H      = 9960704;    // NN*LM u16
constexpr size_t OFF_Y1     = 112360704;  // NN*HC u16
constexpr size_t OFF_Y3     = 125160704;  // NN*OC u16
constexpr size_t OFF_ABF    = 131560704;  // NN*LM u16 (fast path only)
constexpr size_t NEED_FAST  = OFF_ABF + (size_t)NN * LM * 2;  // ~234 MB

// Abf convert chunk partition (each chunk = 8 elems; total NN*LM/8 = 6.4M)
constexpr size_t CVT_TOTAL = (size_t)NN * LM / 8;        // 6,400,000
constexpr size_t CVT_CNT   = 2560000;  // in k_count  (10000 blk x 256)
constexpr size_t CVT_SC1   = 1280000;  // in k_scan1  (1250 blk x 1024)
constexpr size_t CVT_SC3   = 640000;   // in k_scan3  (2500 blk x 256)
constexpr size_t CVT_FIL   = 1920000;  // in k_fill   (7500 blk x 256)

__device__ __forceinline__ u16 f2bf(float f) {
    union { float f; unsigned int u; } a; a.f = f;
    unsigned int u = a.u + 0x7FFFu + ((a.u >> 16) & 1u);  // RNE
    return (u16)(u >> 16);
}
__device__ __forceinline__ float bf2f(u16 v) {
    union { unsigned int u; float f; } a; a.u = ((unsigned int)v) << 16;
    return a.f;
}
__device__ __forceinline__ ushort2 pkbf(float a, float b) {
    union { __hip_bfloat162 h; ushort2 u; } cv;
    cv.h = __float22bfloat162_rn(make_float2(a, b));
    return cv.u;
}
__device__ __forceinline__ void async_copy16(u16* lds, const u16* g) {
    __builtin_amdgcn_global_load_lds(
        (const __attribute__((address_space(1))) void*)g,
        (__attribute__((address_space(3))) void*)lds, 16, 0, 0);
}
// one chunk = 8 fp32 -> 8 bf16
__device__ __forceinline__ void cvt_chunk(size_t idx, const float* __restrict__ A32,
                                          u16* __restrict__ Abf) {
    const float* src = A32 + idx * 8;
    float4 v0 = *(const float4*)(src);
    float4 v1 = *(const float4*)(src + 4);
    union { ushort2 u2[4]; bf16x8 v; } pk2;
    pk2.u2[0] = pkbf(v0.x, v0.y);
    pk2.u2[1] = pkbf(v0.z, v0.w);
    pk2.u2[2] = pkbf(v1.x, v1.y);
    pk2.u2[3] = pkbf(v1.z, v1.w);
    *(bf16x8*)(Abf + idx * 8) = pk2.v;
}

// ====== k_count: edge-count atomics + Wl/W1 converts + Abf chunk share ======
// blocks [0,3125): edge atomics; [3125,4149): WlT transpose; [4149,4661): W1T;
// [4661,14661) fast path: Abf chunks [0, 2.56M).
__global__ void k_count(const int* __restrict__ ei, const float* __restrict__ ew,
                        u64* __restrict__ pk,
                        const float* __restrict__ Wl, u16* __restrict__ WlT,
                        const float* __restrict__ W1, u16* __restrict__ W1T,
                        const float* __restrict__ A32, u16* __restrict__ Abf) {
    int b = blockIdx.x, t = threadIdx.x;
    if (b < 3125) {
        int e = b * 256 + t;
        if (e < NE) {
            int d = ei[NE + e];
            u64 add = (1ULL << 48) | (u64)(ew[e] * 4294967296.0);
            atomicAdd(&pk[d], add);
        }
    } else if (b < 4149) {
        __shared__ float sm[32][33];
        int bb = b - 3125;
        int n0 = (bb & 31) * 32, k0 = (bb >> 5) * 32;
        int ty = t >> 5, tx = t & 31;
        #pragma unroll
        for (int i = 0; i < 4; i++)
            sm[ty + i * 8][tx] = Wl[(size_t)(k0 + ty + i * 8) * LM + n0 + tx];
        __syncthreads();
        #pragma unroll
        for (int i = 0; i < 4; i++)
            WlT[(size_t)(n0 + ty + i * 8) * LM + k0 + tx] = f2bf(sm[tx][ty + i * 8]);
    } else if (b < 4661) {
        int idx = (b - 4149) * 256 + t;  // HC*LM, output-major
        if (idx < HC * LM) {
            int o = idx >> 10, k = idx & 1023;
            W1T[idx] = f2bf(W1[(size_t)k * HC + o]);
        }
    } else {
        cvt_chunk((size_t)(b - 4661) * 256 + t, A32, Abf);
    }
}

// ====== scan1 (+ Abf chunk share [2.56M, 3.84M)) ======
__global__ void k_scan1(const u64* __restrict__ pk, int* __restrict__ incl,
                        int* __restrict__ bsum,
                        const float* __restrict__ A32, u16* __restrict__ Abf) {
    int b = blockIdx.x, t = threadIdx.x;
    if (b >= 49) {
        cvt_chunk(CVT_CNT + (size_t)(b - 49) * 1024 + t, A32, Abf);
        return;
    }
    __shared__ int sm[1024];
    int idx = b * 1024 + t;
    int v = (idx < NN) ? (int)(pk[idx] >> 48) : 0;
    sm[t] = v; __syncthreads();
    for (int off = 1; off < 1024; off <<= 1) {
        int add = (t >= off) ? sm[t - off] : 0;
        __syncthreads();
        sm[t] += add;
        __syncthreads();
    }
    if (idx < NN) incl[idx] = sm[t];
    if (t == 1023) bsum[b] = sm[t];
}

// ====== scan3: rowptr/cursor/dis (+ Abf chunk share [3.84M, 4.48M)) ======
__global__ void k_scan3(const int* __restrict__ incl, const u64* __restrict__ pk,
                        const int* __restrict__ bsum,
                        int* __restrict__ rowptr, int* __restrict__ cursor,
                        float* __restrict__ dis,
                        const float* __restrict__ A32, u16* __restrict__ Abf) {
    int b = blockIdx.x;
    if (b >= 196) {
        cvt_chunk(CVT_CNT + CVT_SC1 + (size_t)(b - 196) * 256 + threadIdx.x, A32, Abf);
        return;
    }
    int seg = b >> 2;
    int lane = threadIdx.x & 63;
    int v = (lane < seg) ? bsum[lane] : 0;  // seg <= 48 < 64
    #pragma unroll
    for (int off = 32; off > 0; off >>= 1) v += __shfl_down(v, off, 64);
    int boffv = __shfl(v, 0, 64);
    int idx = b * 256 + threadIdx.x;
    if (idx < NN) {
        u64 p = pk[idx];
        int cnt = (int)(p >> 48);
        float deg = (float)((double)(p & 0xFFFFFFFFFFFFULL) * 2.3283064365386963e-10);
        int rp = incl[idx] - cnt + boffv;
        rowptr[idx] = rp;
        cursor[idx] = rp;
        dis[idx] = rsqrtf(1.0f + deg);
    } else if (idx == NN) {
        rowptr[NN] = NE;
    }
}

// ====== fill CSR; dis[src] folded into weight (+ Abf chunks [4.48M, 6.4M)) ===
__global__ void k_fill(const int* __restrict__ ei, const float* __restrict__ ew,
                       const float* __restrict__ dis,
                       int* __restrict__ cursor, int2* __restrict__ meta,
                       const float* __restrict__ A32, u16* __restrict__ Abf) {
    int b = blockIdx.x;
    if (b >= 3125) {
        cvt_chunk(CVT_CNT + CVT_SC1 + CVT_SC3 + (size_t)(b - 3125) * 256 + threadIdx.x,
                  A32, Abf);
        return;
    }
    int e = b * 256 + threadIdx.x;
    if (e < NE) {
        int s = ei[e];
        int d = ei[NE + e];
        int slot = atomicAdd(&cursor[d], 1);
        meta[slot] = make_int2(s, __float_as_int(ew[e] * dis[s]));
    }
}

// ======== GEMM1a (fast path): pure-async m97-style 128x128, fused epilogue ====
// Both operands bf16 via global_load_lds; XOR-swizzled LDS (conflicts 0);
// XCD swizzle: 8 n-siblings of an m-band get ids == same mod 8.
__global__ __launch_bounds__(256, 2) void k_gemm1a(
    const u16* __restrict__ Abf, const u16* __restrict__ Bt, u16* __restrict__ Cout,
    const float* __restrict__ xv, const float* __restrict__ cv,
    const float* __restrict__ Wa, const float* __restrict__ Wc,
    const float* __restrict__ bl) {
    __shared__ u16 lA[128 * 64];
    __shared__ u16 lB[128 * 64];
    const int tid = threadIdx.x;
    const int lane = tid & 63, wv = tid >> 6;
    int x = blockIdx.x & 7, j = blockIdx.x >> 3;
    int bx = (j & ~7) | x;
    int by = j & 7;
    if (bx >= 391) return;  // uniform, before any barrier
    const int m0 = bx * 128, n0 = by * 128;
    const int wm = (wv >> 1) * 64, wn = (wv & 1) * 64;
    const int fr = lane & 15, qd = lane >> 4;

    f32x4 acc[4][4] = {};

    for (int kt = 0; kt < 16; kt++) {
        const int k0 = kt << 6;
        __syncthreads();
        #pragma unroll
        for (int i = 0; i < 4; i++) {
            int r0 = i * 32 + wv * 8;
            int rl = r0 + (lane >> 3);
            int slot = lane & 7;
            int k8 = slot ^ (rl & 7);
            const u16* g = Bt + (size_t)(n0 + rl) * LM + k0 + k8 * 8;
            async_copy16(&lB[r0 * 64], g);
        }
        #pragma unroll
        for (int i = 0; i < 4; i++) {
            int r0 = i * 32 + wv * 8;
            int rl = r0 + (lane >> 3);
            int slot = lane & 7;
            int k8 = slot ^ (rl & 7);
            int row = m0 + rl; if (row >= NN) row = NN - 1;
            const u16* g = Abf + (size_t)row * LM + k0 + k8 * 8;
            async_copy16(&lA[r0 * 64], g);
        }
        __syncthreads();
        #pragma unroll
        for (int s = 0; s < 2; s++) {
            const int slot = (s * 4 + qd) ^ (fr & 7);
            bf16x8 af[4], bfm[4];
            #pragma unroll
            for (int mi = 0; mi < 4; mi++)
                af[mi] = *(const bf16x8*)&lA[(wm + mi * 16 + fr) * 64 + slot * 8];
            #pragma unroll
            for (int ni = 0; ni < 4; ni++)
                bfm[ni] = *(const bf16x8*)&lB[(wn + ni * 16 + fr) * 64 + slot * 8];
            #pragma unroll
            for (int mi = 0; mi < 4; mi++)
                #pragma unroll
                for (int ni = 0; ni < 4; ni++)
                    acc[mi][ni] = __builtin_amdgcn_mfma_f32_16x16x32_bf16(
                        af[mi], bfm[ni], acc[mi][ni], 0, 0, 0);
        }
    }

    int jj[4]; float waj[4], wcj[4], blj[4];
    #pragma unroll
    for (int ni = 0; ni < 4; ni++) {
        jj[ni] = n0 + wn + ni * 16 + fr;
        waj[ni] = Wa[jj[ni]]; wcj[ni] = Wc[jj[ni]]; blj[ni] = bl[jj[ni]];
    }
    #pragma unroll
    for (int mi = 0; mi < 4; mi++)
        #pragma unroll
        for (int r = 0; r < 4; r++) {
            int row = m0 + wm + mi * 16 + qd * 4 + r;
            if (row < NN) {
                float xb = xv[row], cb = cv[row];
                #pragma unroll
                for (int ni = 0; ni < 4; ni++) {
                    float v = acc[mi][ni][r] + xb * waj[ni] + cb * wcj[ni] + blj[ni];
                    Cout[(size_t)row * LM + jj[ni]] = f2bf(fmaxf(v, 0.f));
                }
            }
        }
}

// ======== GEMM1f (fallback): 128x256 tile, fp32 A reg-prefetch staging ========
__global__ __launch_bounds__(256, 2) void k_gemm1f(
    const float* __restrict__ A32, const u16* __restrict__ Bt, u16* __restrict__ Cout,
    const float* __restrict__ xv, const float* __restrict__ cv,
    const float* __restrict__ Wa, const float* __restrict__ Wc,
    const float* __restrict__ bl) {
    __shared__ u16 lA[128 * 64];
    __shared__ u16 lB[2][128 * 64];
    const int tid = threadIdx.x;
    const int lane = tid & 63, wv = tid >> 6;
    const int bx = ((blockIdx.x >> 5) << 3) | (blockIdx.x & 7);
    const int by = (blockIdx.x >> 3) & 3;
    if (bx >= 391) return;
    const int m0 = bx * 128, n0 = by * 256;
    const int wm = (wv >> 1) * 64, wn = (wv & 1) * 64;
    const int fr = lane & 15, qd = lane >> 4;

    f32x4 acc[2][4][4] = {};

    int srl[4], sslot[4]; const float* sbase[4];
    float4 pf[8];
    #pragma unroll
    for (int i = 0; i < 4; i++) {
        int cidx = i * 256 + tid;
        srl[i] = cidx >> 3; sslot[i] = cidx & 7;
        int k8 = sslot[i] ^ (srl[i] & 7);
        int row = m0 + srl[i]; if (row >= NN) row = NN - 1;
        sbase[i] = A32 + (size_t)row * LM + k8 * 8;
    }
    #pragma unroll
    for (int i = 0; i < 4; i++) {
        pf[2 * i]     = *(const float4*)(sbase[i]);
        pf[2 * i + 1] = *(const float4*)(sbase[i] + 4);
    }

    for (int kt = 0; kt < 16; kt++) {
        const int k0 = kt << 6;
        __syncthreads();
        #pragma unroll
        for (int h = 0; h < 2; h++)
            #pragma unroll
            for (int i = 0; i < 4; i++) {
                int r0 = i * 32 + wv * 8;
                int rl = r0 + (lane >> 3);
                int slot = lane & 7;
                int k8 = slot ^ (rl & 7);
                const u16* g = Bt + (size_t)(n0 + h * 128 + rl) * LM + k0 + k8 * 8;
                async_copy16(&lB[h][r0 * 64], g);
            }
        #pragma unroll
        for (int i = 0; i < 4; i++) {
            union { ushort2 u2[4]; bf16x8 v; } pk;
            pk.u2[0] = pkbf(pf[2 * i].x, pf[2 * i].y);
            pk.u2[1] = pkbf(pf[2 * i].z, pf[2 * i].w);
            pk.u2[2] = pkbf(pf[2 * i + 1].x, pf[2 * i + 1].y);
            pk.u2[3] = pkbf(pf[2 * i + 1].z, pf[2 * i + 1].w);
            *(bf16x8*)&lA[srl[i] * 64 + sslot[i] * 8] = pk.v;
        }
        __syncthreads();
        if (kt < 15) {
            #pragma unroll
            for (int i = 0; i < 4; i++) {
                pf[2 * i]     = *(const float4*)(sbase[i] + k0 + 64);
                pf[2 * i + 1] = *(const float4*)(sbase[i] + k0 + 68);
            }
        }
        #pragma unroll
        for (int s = 0; s < 2; s++) {
            const int slot = (s * 4 + qd) ^ (fr & 7);
            bf16x8 af[4];
            #pragma unroll
            for (int mi = 0; mi < 4; mi++)
                af[mi] = *(const bf16x8*)&lA[(wm + mi * 16 + fr) * 64 + slot * 8];
            #pragma unroll
            for (int h = 0; h < 2; h++) {
                bf16x8 bfm[4];
                #pragma unroll
                for (int ni = 0; ni < 4; ni++)
                    bfm[ni] = *(const bf16x8*)&lB[h][(wn + ni * 16 + fr) * 64 + slot * 8];
                #pragma unroll
                for (int mi = 0; mi < 4; mi++)
                    #pragma unroll
                    for (int ni = 0; ni < 4; ni++)
                        acc[h][mi][ni] = __builtin_amdgcn_mfma_f32_16x16x32_bf16(
                            af[mi], bfm[ni], acc[h][mi][ni], 0, 0, 0);
            }
        }
    }

    #pragma unroll
    for (int h = 0; h < 2; h++) {
        int jj[4]; float waj[4], wcj[4], blj[4];
        #pragma unroll
        for (int ni = 0; ni < 4; ni++) {
            jj[ni] = n0 + h * 128 + wn + ni * 16 + fr;
            waj[ni] = Wa[jj[ni]]; wcj[ni] = Wc[jj[ni]]; blj[ni] = bl[jj[ni]];
        }
        #pragma unroll
        for (int mi = 0; mi < 4; mi++)
            #pragma unroll
            for (int r = 0; r < 4; r++) {
                int row = m0 + wm + mi * 16 + qd * 4 + r;
                if (row < NN) {
                    float xb = xv[row], cb = cv[row];
                    #pragma unroll
                    for (int ni = 0; ni < 4; ni++) {
                        float v = acc[h][mi][ni][r] + xb * waj[ni] + cb * wcj[ni] + blj[ni];
                        Cout[(size_t)row * LM + jj[ni]] = f2bf(fmaxf(v, 0.f));
                    }
                }
            }
    }
}

// ======== GEMM2: y1 = h @ W1, 64x128 tile ========
__global__ __launch_bounds__(256) void k_gemm2(
    const u16* __restrict__ Abf, const u16* __restrict__ Bt, u16* __restrict__ Cout) {
    __shared__ u16 lA[64 * 64];
    __shared__ u16 lB[128 * 64];
    const int tid = threadIdx.x;
    const int lane = tid & 63, wv = tid >> 6;
    const int m0 = blockIdx.x * 64;
    const int wm = (wv >> 1) * 32, wn = (wv & 1) * 64;
    const int fr = lane & 15, qd = lane >> 4;
    f32x4 acc[2][4] = {};

    for (int kt = 0; kt < 16; kt++) {
        const int k0 = kt << 6;
        __syncthreads();
        #pragma unroll
        for (int i = 0; i < 4; i++) {
            int r0 = i * 32 + wv * 8;
            int rl = r0 + (lane >> 3);
            int slot = lane & 7;
            int k8 = slot ^ (rl & 7);
            const u16* g = Bt + (size_t)rl * LM + k0 + k8 * 8;
            async_copy16(&lB[r0 * 64], g);
        }
        #pragma unroll
        for (int i = 0; i < 2; i++) {
            int r0 = i * 32 + wv * 8;
            int rl = r0 + (lane >> 3);
            int slot = lane & 7;
            int k8 = slot ^ (rl & 7);
            int row = m0 + rl; if (row >= NN) row = NN - 1;
            const u16* g = Abf + (size_t)row * LM + k0 + k8 * 8;
            async_copy16(&lA[r0 * 64], g);
        }
        __syncthreads();
        #pragma unroll
        for (int s = 0; s < 2; s++) {
            const int slot = (s * 4 + qd) ^ (fr & 7);
            bf16x8 af[2], bfm[4];
            #pragma unroll
            for (int mi = 0; mi < 2; mi++)
                af[mi] = *(const bf16x8*)&lA[(wm + mi * 16 + fr) * 64 + slot * 8];
            #pragma unroll
            for (int ni = 0; ni < 4; ni++)
                bfm[ni] = *(const bf16x8*)&lB[(wn + ni * 16 + fr) * 64 + slot * 8];
            #pragma unroll
            for (int mi = 0; mi < 2; mi++)
                #pragma unroll
                for (int ni = 0; ni < 4; ni++)
                    acc[mi][ni] = __builtin_amdgcn_mfma_f32_16x16x32_bf16(
                        af[mi], bfm[ni], acc[mi][ni], 0, 0, 0);
        }
    }
    #pragma unroll
    for (int mi = 0; mi < 2; mi++)
        #pragma unroll
        for (int r = 0; r < 4; r++) {
            int row = m0 + wm + mi * 16 + qd * 4 + r;
            if (row < NN) {
                #pragma unroll
                for (int ni = 0; ni < 4; ni++)
                    Cout[(size_t)row * HC + wn + ni * 16 + fr] = f2bf(acc[mi][ni][r]);
            }
        }
}

// ====== fused agg1 + gemm3 ======
// v2: W3 staged to LDS once per block; dot phase uses 2 waves x 4-node reuse
// (each W3 element loaded once per 4 nodes) -> kills the per-wave 32KB W3
// L1/L2 streaming (was ~1.6 GB aggregate). FMA order per node identical to v1
// (k ascending, single fp32 acc) -> bit-identical results.
__global__ __launch_bounds__(512) void k_agg1g3(
    const u16* __restrict__ y1, const int* __restrict__ rowptr,
    const int2* __restrict__ meta, const float* __restrict__ dis,
    const float* __restrict__ b1, const float* __restrict__ W3,
    u16* __restrict__ y3) {
    __shared__ float hrow[8][HC];      // 4 KB
    __shared__ float w3s[HC * OC];     // 32 KB
    const int tid = threadIdx.x;
    const int wv = tid >> 6, lane = tid & 63;
    // stage W3 (8192 f32): 512 thr x 16
    #pragma unroll
    for (int i = 0; i < 16; i++) w3s[i * 512 + tid] = W3[i * 512 + tid];
    // gather phase: one wave per node (grid 6250 x 8 = NN exactly; no returns)
    int node = blockIdx.x * 8 + wv;
    float di = dis[node];
    int p0 = rowptr[node], p1 = rowptr[node + 1];
    ushort2 sv = *(const ushort2*)(y1 + (size_t)node * HC + lane * 2);
    float a0 = di * bf2f(sv.x), a1 = di * bf2f(sv.y);
    #pragma unroll 8
    for (int p = p0; p < p1; ++p) {
        int2 m = meta[p];
        float nm = __int_as_float(m.y);
        ushort2 v = *(const ushort2*)(y1 + (size_t)m.x * HC + lane * 2);
        a0 += nm * bf2f(v.x);
        a1 += nm * bf2f(v.y);
    }
    a0 = fmaxf(di * a0 + b1[lane * 2], 0.f);
    a1 = fmaxf(di * a1 + b1[lane * 2 + 1], 0.f);
    hrow[wv][lane * 2] = a0;
    hrow[wv][lane * 2 + 1] = a1;
    __syncthreads();
    // dot phase: waves 0,1 each compute 4 nodes x 64 outs; W3 loaded once/4 nodes
    if (wv < 2) {
        const int nb = wv * 4;
        float c0 = 0.f, c1 = 0.f, c2 = 0.f, c3 = 0.f;
        #pragma unroll 4
        for (int k = 0; k < HC; ++k) {
            float w = w3s[k * OC + lane];   // 2-way bank alias = free
            c0 += hrow[nb][k] * w;          // broadcast reads
            c1 += hrow[nb + 1][k] * w;
            c2 += hrow[nb + 2][k] * w;
            c3 += hrow[nb + 3][k] * w;
        }
        size_t base = (size_t)(blockIdx.x * 8 + nb) * OC + lane;
        y3[base]          = f2bf(c0);
        y3[base + OC]     = f2bf(c1);
        y3[base + 2 * OC] = f2bf(c2);
        y3[base + 3 * OC] = f2bf(c3);
    }
}

// ================= aggregation 3 =================
__global__ __launch_bounds__(256) void k_agg3(
    const u16* __restrict__ y3, const int* __restrict__ rowptr,
    const int2* __restrict__ meta, const float* __restrict__ dis,
    const float* __restrict__ b3, float* __restrict__ outp) {
    int node = blockIdx.x * 4 + (threadIdx.x >> 6);
    int lane = threadIdx.x & 63;
    if (node >= NN) return;
    float di = dis[node];
    int p0 = rowptr[node], p1 = rowptr[node + 1];
    float a = di * bf2f(y3[(size_t)node * OC + lane]);
    #pragma unroll 8
    for (int p = p0; p < p1; ++p) {
        int2 m = meta[p];
        a += __int_as_float(m.y) * bf2f(y3[(size_t)m.x * OC + lane]);
    }
    outp[(size_t)node * OC + lane] = di * a + b3[lane];
}

extern "C" void kernel_launch(void* const* d_in, const int* in_sizes, int n_in,
                              void* d_out, int out_size, void* d_ws, size_t ws_size,
                              hipStream_t stream) {
    const float* x    = (const float*)d_in[0];
    const float* xout = (const float*)d_in[1];
    const float* c    = (const float*)d_in[2];
    const int*   ei   = (const int*)d_in[3];
    const float* ew   = (const float*)d_in[4];
    const float* Wa   = (const float*)d_in[5];
    const float* Wc   = (const float*)d_in[6];
    const float* Wl   = (const float*)d_in[7];
    const float* bl   = (const float*)d_in[8];
    const float* W1   = (const float*)d_in[9];
    const float* b1   = (const float*)d_in[10];
    const float* W3   = (const float*)d_in[11];
    const float* b3   = (const float*)d_in[12];
    float* outp = (float*)d_out;

    char* ws = (char*)d_ws;
    int*   rowptr = (int*)(ws + OFF_ROWPTR);
    int*   cursor = (int*)(ws + OFF_CURSOR);
    u64*   pk     = (u64*)(ws + OFF_PK);
    int*   incl   = (int*)(ws + OFF_INCL);
    int*   bsum   = (int*)(ws + OFF_BSUM);
    float* dis    = (float*)(ws + OFF_DIS);
    int2*  meta   = (int2*)(ws + OFF_META);
    u16*   WlT    = (u16*)(ws + OFF_WLT);
    u16*   W1T    = (u16*)(ws + OFF_W1T);
    u16*   hbuf   = (u16*)(ws + OFF_H);
    u16*   y1     = (u16*)(ws + OFF_Y1);
    u16*   y3     = (u16*)(ws + OFF_Y3);
    u16*   Abf    = (u16*)(ws + OFF_ABF);

    const bool fast = (ws_size >= NEED_FAST);

    // pk zero via memset (replaces k_zero dispatch; must precede count atomics)
    hipMemsetAsync(pk, 0, (size_t)NN * sizeof(u64), stream);
    // CSR chain with the x_out bf16 convert riding in otherwise-idle CUs:
    // count carries Wl/W1 converts + 2.56M chunks; scan1 +1.28M; scan3 +0.64M;
    // fill +1.92M. All Abf work completes before k_gemm1a (stream order).
    k_count<<<fast ? 14661 : 4661, 256, 0, stream>>>(ei, ew, pk, Wl, WlT, W1, W1T,
                                                     xout, Abf);
    k_scan1<<<fast ? 1299 : 49, 1024, 0, stream>>>(pk, incl, bsum, xout, Abf);
    k_scan3<<<fast ? 2696 : 196, 256, 0, stream>>>(incl, pk, bsum, rowptr, cursor,
                                                   dis, xout, Abf);
    k_fill <<<fast ? 10625 : 3125, 256, 0, stream>>>(ei, ew, dis, cursor, meta,
                                                     xout, Abf);

    if (fast) {
        k_gemm1a<<<392 * 8, 256, 0, stream>>>(Abf, WlT, hbuf, x, c, Wa, Wc, bl);
    } else {
        k_gemm1f<<<49 * 32, 256, 0, stream>>>(xout, WlT, hbuf, x, c, Wa, Wc, bl);
    }
    // GEMM2: y1 = h @ W1
    k_gemm2<<<782, 256, 0, stream>>>(hbuf, W1T, y1);
    // conv1 aggregation + bias + relu + conv3 linear (fused)
    k_agg1g3<<<6250, 512, 0, stream>>>(y1, rowptr, meta, dis, b1, W3, y3);
    // conv3 aggregation + bias -> out
    k_agg3<<<12500, 256, 0, stream>>>(y3, rowptr, meta, dis, b3, outp);
}